// Round 17
// baseline (210.017 us; speedup 1.0000x reference)
//
#include <hip/hip_runtime.h>

// GCN 3-layer forward on MI355X.
// CSR build WITHOUT global atomics; all matmuls on MFMA; 9 dispatches:
//   D1: hist_rank + prep_w        D2-4: hierarchical scan
//   D5: scatter_part + mm1 (fp32->bf16 A in-reg) -> xb1
//   D6: bucket -> row_ptr/col/norms
//   D7: FUSED agg+act+MFMA@W2 -> xb2   (wave-private LDS tile, NO barrier)
//   D8: FUSED agg+act+MFMA@W3 -> yb    (pad 40->64)
//   D9: agg40 -> out fp32
// aggmm v2: one wave owns 16 nodes end-to-end (agg -> private 16x136 LDS ->
// full-width MFMA). 8 edges/iter octant gather (32B/lane) for 2x inflight lines.

#define EPB 4096
#define SCAN_CHUNK 4096

typedef short v8s __attribute__((ext_vector_type(8)));
typedef float v4f __attribute__((ext_vector_type(4)));

__device__ __forceinline__ ushort f2bf(float f) {
    unsigned u = __float_as_uint(f);
    unsigned r = (u + 0x7fffu + ((u >> 16) & 1u)) >> 16;  // RN-even
    return (ushort)r;
}
__device__ __forceinline__ void unpack2(unsigned w, float& lo, float& hi) {
    lo = __uint_as_float(w << 16);
    hi = __uint_as_float(w & 0xffff0000u);
}

// ---------------- D1: hist_rank + prep_w (fused) ----------------
__global__ __launch_bounds__(256) void front_kernel(const int* __restrict__ ei, int E,
        int nblk1, int NB, int* __restrict__ hist_all,
        ushort* __restrict__ rankD, ushort* __restrict__ rankS,
        const float* __restrict__ W1, const float* __restrict__ W2,
        const float* __restrict__ W3,
        ushort* __restrict__ W1f, ushort* __restrict__ W2f, ushort* __restrict__ W3f) {
    __shared__ int hd[512];
    __shared__ int hs[512];
    int t = threadIdx.x;
    if ((int)blockIdx.x >= nblk1) {
        int idx = ((int)blockIdx.x - nblk1) * 256 + t;
        const float* W; ushort* Wf; int Dout, NF, base;
        if (idx < 2048)      { W = W1; Wf = W1f; Dout = 128; NF = 8; base = idx; }
        else if (idx < 4096) { W = W2; Wf = W2f; Dout = 128; NF = 8; base = idx - 2048; }
        else if (idx < 5120) { W = W3; Wf = W3f; Dout = 40;  NF = 4; base = idx - 4096; }
        else return;
        int lane = base & 63;
        int f = (base >> 6) % NF;
        int ks = base / (64 * NF);
        int c = f * 16 + (lane & 15);
        int kbase = ks * 32 + (lane >> 4) * 8;
        unsigned p[4];
        #pragma unroll
        for (int j = 0; j < 4; ++j) {
            float wlo = (c < Dout) ? W[(size_t)(kbase + 2 * j) * Dout + c] : 0.f;
            float whi = (c < Dout) ? W[(size_t)(kbase + 2 * j + 1) * Dout + c] : 0.f;
            p[j] = (unsigned)f2bf(wlo) | ((unsigned)f2bf(whi) << 16);
        }
        *reinterpret_cast<uint4*>(Wf + (size_t)base * 8) = make_uint4(p[0], p[1], p[2], p[3]);
        return;
    }
    int blk = blockIdx.x;
    for (int i = t; i < 512; i += 256) { hd[i] = 0; hs[i] = 0; }
    __syncthreads();
    int base = blk * EPB;
    #pragma unroll
    for (int j = 0; j < 16; ++j) {
        int e = base + j * 256 + t;
        if (e < E) {
            int s = ei[e], d = ei[E + e];
            rankS[e] = (ushort)atomicAdd(&hs[s >> 8], 1);
            rankD[e] = (ushort)atomicAdd(&hd[d >> 8], 1);
        }
    }
    __syncthreads();
    int L = NB * nblk1;
    for (int b = t; b < NB; b += 256) {
        hist_all[b * nblk1 + blk]     = hd[b];
        hist_all[L + b * nblk1 + blk] = hs[b];
    }
}

// ---------------- scan ----------------
__global__ __launch_bounds__(256) void scanA_kernel(const int* __restrict__ data, int L2,
                                                    int* __restrict__ partials) {
    __shared__ int red[256];
    int t = threadIdx.x;
    int base = blockIdx.x * SCAN_CHUNK;
    int s = 0;
    for (int i = t; i < SCAN_CHUNK; i += 256) {
        int idx = base + i;
        if (idx < L2) s += data[idx];
    }
    red[t] = s;
    __syncthreads();
    for (int off = 128; off > 0; off >>= 1) {
        if (t < off) red[t] += red[t + off];
        __syncthreads();
    }
    if (t == 0) partials[blockIdx.x] = red[0];
}

__global__ __launch_bounds__(256) void scanB_kernel(int* __restrict__ partials, int nparts) {
    __shared__ int s[256];
    int t = threadIdx.x;
    s[t] = (t < nparts) ? partials[t] : 0;
    __syncthreads();
    for (int off = 1; off < 256; off <<= 1) {
        int v = (t >= off) ? s[t - off] : 0;
        __syncthreads();
        s[t] += v;
        __syncthreads();
    }
    if (t < nparts) partials[t] = s[t] - partials[t];
}

__global__ __launch_bounds__(256) void scanC_kernel(int* __restrict__ data, int L2,
                                                    const int* __restrict__ partials) {
    __shared__ int tsum[256];
    int t = threadIdx.x;
    int base = blockIdx.x * SCAN_CHUNK + t * 16;
    int local[16];
    int s = 0;
    #pragma unroll
    for (int i = 0; i < 16; ++i) {
        int idx = base + i;
        int v = (idx < L2) ? data[idx] : 0;
        local[i] = v;
        s += v;
    }
    tsum[t] = s;
    __syncthreads();
    for (int off = 1; off < 256; off <<= 1) {
        int v = (t >= off) ? tsum[t - off] : 0;
        __syncthreads();
        tsum[t] += v;
        __syncthreads();
    }
    int run = partials[blockIdx.x] + (t ? tsum[t - 1] : 0);
    #pragma unroll
    for (int i = 0; i < 16; ++i) {
        int idx = base + i;
        if (idx < L2) {
            data[idx] = run;
            run += local[i];
        }
    }
}

// ---------------- MFMA matmul body (global-A, for mm1) ----------------
template<int NF, int DO_NS, int FP32IN>
__device__ __forceinline__ void mm_body(const void* __restrict__ Xv,
        const ushort* __restrict__ Wf, const float* __restrict__ ns,
        ushort* __restrict__ out, int n, int blk, int wv, int lane) {
    int row0 = (blk * 4 + wv) * 16;
    if (row0 >= n) return;
    int arow = row0 + (lane & 15);
    if (arow >= n) arow = n - 1;
    int kgrp = lane >> 4;
    const v8s* bp = reinterpret_cast<const v8s*>(Wf);
    v4f acc[NF];
    #pragma unroll
    for (int f = 0; f < NF; ++f) acc[f] = (v4f){0.f, 0.f, 0.f, 0.f};
    #pragma unroll
    for (int ks = 0; ks < 4; ++ks) {
        v8s a;
        if (FP32IN) {
            const float* xp = (const float*)Xv + (size_t)arow * 128 + (ks * 4 + kgrp) * 8;
            float4 lo = *reinterpret_cast<const float4*>(xp);
            float4 hi = *reinterpret_cast<const float4*>(xp + 4);
            a[0] = (short)f2bf(lo.x); a[1] = (short)f2bf(lo.y);
            a[2] = (short)f2bf(lo.z); a[3] = (short)f2bf(lo.w);
            a[4] = (short)f2bf(hi.x); a[5] = (short)f2bf(hi.y);
            a[6] = (short)f2bf(hi.z); a[7] = (short)f2bf(hi.w);
        } else {
            const v8s* ap = reinterpret_cast<const v8s*>((const ushort*)Xv + (size_t)arow * 128);
            a = ap[ks * 4 + kgrp];
        }
        #pragma unroll
        for (int f = 0; f < NF; ++f) {
            v8s b = bp[(ks * NF + f) * 64 + lane];
            acc[f] = __builtin_amdgcn_mfma_f32_16x16x32_bf16(a, b, acc[f], 0, 0, 0);
        }
    }
    int rbase = row0 + (lane >> 4) * 4;
    int ccol = lane & 15;
    constexpr int OS = NF * 16;
    #pragma unroll
    for (int r = 0; r < 4; ++r) {
        int gr = rbase + r;
        if (gr < n) {
            float s = DO_NS ? ns[gr] : 1.f;
            #pragma unroll
            for (int f = 0; f < NF; ++f)
                out[(size_t)gr * OS + f * 16 + ccol] = f2bf(s * acc[f][r]);
        }
    }
}

// ---------------- D5: scatter_part + mm1 (fused) ----------------
__global__ __launch_bounds__(256) void scatter_mm1_kernel(const int* __restrict__ ei, int E,
        int nblk1, int NB, const int* __restrict__ hist_all,
        const ushort* __restrict__ rankD, const ushort* __restrict__ rankS,
        unsigned* __restrict__ packD, unsigned char* __restrict__ srcb,
        const float* __restrict__ features, const ushort* __restrict__ W1f,
        ushort* __restrict__ xb, int n) {
    int t = threadIdx.x;
    if ((int)blockIdx.x >= nblk1) {
        int blk = (int)blockIdx.x - nblk1;
        mm_body<8, 0, 1>(features, W1f, nullptr, xb, n, blk, t >> 6, t & 63);
        return;
    }
    int blk = blockIdx.x;
    int base = blk * EPB;
    int L = NB * nblk1;
    #pragma unroll
    for (int j = 0; j < 16; ++j) {
        int e = base + j * 256 + t;
        if (e < E) {
            int s = ei[e], d = ei[E + e];
            int posD = hist_all[(d >> 8) * nblk1 + blk] + (int)rankD[e];
            packD[posD] = ((unsigned)(d & 255) << 24) | (unsigned)s;
            int posS = hist_all[L + (s >> 8) * nblk1 + blk] - E + (int)rankS[e];
            srcb[posS] = (unsigned char)(s & 255);
        }
    }
}

// ---------------- D6: bucket ----------------
__global__ __launch_bounds__(256) void bucket_kernel(const unsigned* __restrict__ packD,
        const unsigned char* __restrict__ srcb, const int* __restrict__ hist_all,
        int nblk1, int NB, int n, int E,
        int* __restrict__ row_ptr, int* __restrict__ col,
        float* __restrict__ norm_src, float* __restrict__ norm_dst) {
    int t = threadIdx.x;
    __shared__ int cnt[256];
    __shared__ int incl[256];
    __shared__ int cur[256];
    if ((int)blockIdx.x < NB) {
        int B = blockIdx.x;
        int s0 = hist_all[B * nblk1];
        int s1 = (B + 1 < NB) ? hist_all[(B + 1) * nblk1] : E;
        cnt[t] = 0;
        __syncthreads();
        for (int i = s0 + t; i < s1; i += 256)
            atomicAdd(&cnt[packD[i] >> 24], 1);
        __syncthreads();
        int v = cnt[t];
        incl[t] = v;
        __syncthreads();
        for (int off = 1; off < 256; off <<= 1) {
            int w = (t >= off) ? incl[t - off] : 0;
            __syncthreads();
            incl[t] += w;
            __syncthreads();
        }
        int excl = incl[t] - v;
        cur[t] = excl;
        int node = B * 256 + t;
        if (node < n) {
            row_ptr[node] = s0 + excl;
            norm_dst[node] = rsqrtf((float)(v > 0 ? v : 1));
        }
        if (B == NB - 1 && t == 0) row_ptr[n] = E;
        __syncthreads();
        for (int i = s0 + t; i < s1; i += 256) {
            unsigned p = packD[i];
            int r = atomicAdd(&cur[p >> 24], 1);
            col[s0 + r] = (int)(p & 0xFFFFFFu);
        }
    } else {
        int B = (int)blockIdx.x - NB;
        int L = NB * nblk1;
        int s0 = hist_all[L + B * nblk1] - E;
        int s1 = (B + 1 < NB) ? (hist_all[L + (B + 1) * nblk1] - E) : E;
        cnt[t] = 0;
        __syncthreads();
        for (int i = s0 + t; i < s1; i += 256)
            atomicAdd(&cnt[srcb[i]], 1);
        __syncthreads();
        int node = B * 256 + t;
        if (node < n) {
            int v = cnt[t];
            norm_src[node] = rsqrtf((float)(v > 0 ? v : 1));
        }
    }
}

// ---------------- D7/D8: FUSED agg + MFMA, wave-private (NO barrier) ----------------
// Wave wv owns nodes vbase..vbase+15. Gather: 8 edges/iter, lane=oct*8+l8,
// 32B/lane (dims 16*l8..+15). Reduce shfl_xor 8/16/32; lanes oct==0 write
// activated bf16 row (32B) to the wave-private LDS tile [16][136]. Then the
// SAME wave runs the full-width MFMA from its tile (lgkmcnt only, no barrier).
template<int EDGE_NS, int ACT_NS, int NF, int MM_NS, int PAD40>
__global__ __launch_bounds__(256) void aggmm_kernel(const ushort* __restrict__ xt,
        const int* __restrict__ row_ptr, const int* __restrict__ col,
        const float* __restrict__ bias, const float* __restrict__ norm_dst,
        const float* __restrict__ norm_src, const ushort* __restrict__ Wf,
        ushort* __restrict__ out, int n) {
    __shared__ ushort Xl[4][16][136];
    int t = threadIdx.x;
    int wv = t >> 6, lane = t & 63;
    int vbase = ((int)blockIdx.x * 4 + wv) * 16;
    if (vbase >= n) return;
    int oct = lane >> 3, l8 = lane & 7;
    for (int i = 0; i < 16; ++i) {
        int vi = vbase + i;
        if (vi < n) {
            int start = row_ptr[vi], end = row_ptr[vi + 1];
            float acc[16];
            #pragma unroll
            for (int q = 0; q < 16; ++q) acc[q] = 0.f;
            for (int b = start; b < end; b += 64) {
                int m = end - b; if (m > 64) m = 64;
                int u = 0; float s = 1.f;
                if (lane < m) {
                    u = col[b + lane];
                    if (EDGE_NS) s = norm_src[u];
                }
                for (int j = 0; j < m; j += 8) {
                    int jj = j + oct;
                    int uu = __shfl(u, jj);
                    float ss = EDGE_NS ? __shfl(s, jj) : 1.f;
                    if (jj < m) {
                        const ushort* rp = xt + (size_t)uu * 128 + 16 * l8;
                        uint4 v0 = *reinterpret_cast<const uint4*>(rp);
                        uint4 v1 = *reinterpret_cast<const uint4*>(rp + 8);
                        float f0, f1;
                        if (EDGE_NS) {
                            unpack2(v0.x, f0, f1); acc[0]  = fmaf(ss, f0, acc[0]);  acc[1]  = fmaf(ss, f1, acc[1]);
                            unpack2(v0.y, f0, f1); acc[2]  = fmaf(ss, f0, acc[2]);  acc[3]  = fmaf(ss, f1, acc[3]);
                            unpack2(v0.z, f0, f1); acc[4]  = fmaf(ss, f0, acc[4]);  acc[5]  = fmaf(ss, f1, acc[5]);
                            unpack2(v0.w, f0, f1); acc[6]  = fmaf(ss, f0, acc[6]);  acc[7]  = fmaf(ss, f1, acc[7]);
                            unpack2(v1.x, f0, f1); acc[8]  = fmaf(ss, f0, acc[8]);  acc[9]  = fmaf(ss, f1, acc[9]);
                            unpack2(v1.y, f0, f1); acc[10] = fmaf(ss, f0, acc[10]); acc[11] = fmaf(ss, f1, acc[11]);
                            unpack2(v1.z, f0, f1); acc[12] = fmaf(ss, f0, acc[12]); acc[13] = fmaf(ss, f1, acc[13]);
                            unpack2(v1.w, f0, f1); acc[14] = fmaf(ss, f0, acc[14]); acc[15] = fmaf(ss, f1, acc[15]);
                        } else {
                            unpack2(v0.x, f0, f1); acc[0]  += f0; acc[1]  += f1;
                            unpack2(v0.y, f0, f1); acc[2]  += f0; acc[3]  += f1;
                            unpack2(v0.z, f0, f1); acc[4]  += f0; acc[5]  += f1;
                            unpack2(v0.w, f0, f1); acc[6]  += f0; acc[7]  += f1;
                            unpack2(v1.x, f0, f1); acc[8]  += f0; acc[9]  += f1;
                            unpack2(v1.y, f0, f1); acc[10] += f0; acc[11] += f1;
                            unpack2(v1.z, f0, f1); acc[12] += f0; acc[13] += f1;
                            unpack2(v1.w, f0, f1); acc[14] += f0; acc[15] += f1;
                        }
                    }
                }
            }
            #pragma unroll
            for (int q = 0; q < 16; ++q) {
                acc[q] += __shfl_xor(acc[q], 8);
                acc[q] += __shfl_xor(acc[q], 16);
                acc[q] += __shfl_xor(acc[q], 32);
            }
            if (oct == 0) {
                float nd = norm_dst[vi];
                float sc = ACT_NS ? norm_src[vi] : 1.f;
                const float* bp = bias + 16 * l8;
                unsigned p[8];
                #pragma unroll
                for (int q = 0; q < 8; ++q) {
                    float lo = fmaxf(fmaf(nd, acc[2 * q],     bp[2 * q]),     0.f) * sc;
                    float hi = fmaxf(fmaf(nd, acc[2 * q + 1], bp[2 * q + 1]), 0.f) * sc;
                    p[q] = (unsigned)f2bf(lo) | ((unsigned)f2bf(hi) << 16);
                }
                uint4* lp = reinterpret_cast<uint4*>(&Xl[wv][i][16 * l8]);
                lp[0] = make_uint4(p[0], p[1], p[2], p[3]);
                lp[1] = make_uint4(p[4], p[5], p[6], p[7]);
            }
        } else if (oct == 0) {
            uint4* lp = reinterpret_cast<uint4*>(&Xl[wv][i][16 * l8]);
            lp[0] = make_uint4(0, 0, 0, 0);
            lp[1] = make_uint4(0, 0, 0, 0);
        }
    }
    // Same-wave LDS dependency: compiler-inserted lgkmcnt, no __syncthreads.
    const v8s* bp2 = reinterpret_cast<const v8s*>(Wf);
    int kgrp = lane >> 4;
    v4f macc[NF];
    #pragma unroll
    for (int f = 0; f < NF; ++f) macc[f] = (v4f){0.f, 0.f, 0.f, 0.f};
    #pragma unroll
    for (int ks = 0; ks < 4; ++ks) {
        v8s a = *reinterpret_cast<const v8s*>(&Xl[wv][lane & 15][(ks * 4 + kgrp) * 8]);
        #pragma unroll
        for (int f = 0; f < NF; ++f) {
            v8s b = bp2[(ks * NF + f) * 64 + lane];
            macc[f] = __builtin_amdgcn_mfma_f32_16x16x32_bf16(a, b, macc[f], 0, 0, 0);
        }
    }
    int rbase = vbase + (lane >> 4) * 4;
    int ccol = lane & 15;
    constexpr int OS = NF * 16;
    #pragma unroll
    for (int r = 0; r < 4; ++r) {
        int gr = rbase + r;
        if (gr < n) {
            float s = MM_NS ? norm_src[gr] : 1.f;
            #pragma unroll
            for (int f = 0; f < NF; ++f) {
                int colo = f * 16 + ccol;
                ushort val = f2bf(s * macc[f][r]);
                if (PAD40 && colo >= 40) val = 0;
                out[(size_t)gr * OS + colo] = val;
            }
        }
    }
}

// ---------------- D9: agg40 ----------------
__global__ __launch_bounds__(256) void agg40_kernel(const ushort* __restrict__ yb,
        const int* __restrict__ row_ptr, const int* __restrict__ col,
        const float* __restrict__ norm_dst, const float* __restrict__ b3,
        float* __restrict__ out, int n) {
    int wid  = (blockIdx.x * blockDim.x + threadIdx.x) >> 6;
    int lane = threadIdx.x & 63;
    if (wid >= n) return;
    int start = row_ptr[wid], end = row_ptr[wid + 1];
    int oct = lane >> 3, l8 = lane & 7;
    float acc[8];
    #pragma unroll
    for (int i = 0; i < 8; ++i) acc[i] = 0.f;
    for (int b = start; b < end; b += 64) {
        int m = end - b; if (m > 64) m = 64;
        int u = 0;
        if (lane < m) u = col[b + lane];
        for (int j = 0; j < m; j += 8) {
            int jj = j + oct;
            int uu = __shfl(u, jj);
            if (jj < m) {
                const uint4 v = *reinterpret_cast<const uint4*>(yb + (size_t)uu * 64 + 8 * l8);
                float f0, f1;
                unpack2(v.x, f0, f1); acc[0] += f0; acc[1] += f1;
                unpack2(v.y, f0, f1); acc[2] += f0; acc[3] += f1;
                unpack2(v.z, f0, f1); acc[4] += f0; acc[5] += f1;
                unpack2(v.w, f0, f1); acc[6] += f0; acc[7] += f1;
            }
        }
    }
    #pragma unroll
    for (int i = 0; i < 8; ++i) {
        acc[i] += __shfl_xor(acc[i], 8);
        acc[i] += __shfl_xor(acc[i], 16);
        acc[i] += __shfl_xor(acc[i], 32);
    }
    if (lane < 5) {
        float nd = norm_dst[wid];
        const float* bp = b3 + 8 * lane;
        float* op = out + (size_t)wid * 40 + 8 * lane;
        float4 o0, o1;
        o0.x = fmaf(nd, acc[0], bp[0]); o0.y = fmaf(nd, acc[1], bp[1]);
        o0.z = fmaf(nd, acc[2], bp[2]); o0.w = fmaf(nd, acc[3], bp[3]);
        o1.x = fmaf(nd, acc[4], bp[4]); o1.y = fmaf(nd, acc[5], bp[5]);
        o1.z = fmaf(nd, acc[6], bp[6]); o1.w = fmaf(nd, acc[7], bp[7]);
        *reinterpret_cast<float4*>(op)     = o0;
        *reinterpret_cast<float4*>(op + 4) = o1;
    }
}

extern "C" void kernel_launch(void* const* d_in, const int* in_sizes, int n_in,
                              void* d_out, int out_size, void* d_ws, size_t ws_size,
                              hipStream_t stream) {
    const float* features = (const float*)d_in[0];
    const int*   ei       = (const int*)d_in[1];
    const float* W1 = (const float*)d_in[2];
    const float* b1 = (const float*)d_in[3];
    const float* W2 = (const float*)d_in[4];
    const float* b2 = (const float*)d_in[5];
    const float* W3 = (const float*)d_in[6];
    const float* b3 = (const float*)d_in[7];

    const int n = in_sizes[0] / 128;
    const int E = in_sizes[1] / 2;

    const int nblk1 = (E + EPB - 1) / EPB;
    const int NB    = (n + 255) >> 8;
    const int L     = NB * nblk1;
    const int L2    = 2 * L;
    const int sb2   = (L2 + SCAN_CHUNK - 1) / SCAN_CHUNK;

    char* w = (char*)d_ws;
    auto alloc = [&](size_t bytes) {
        char* p = w;
        w += (bytes + 255) & ~(size_t)255;
        return p;
    };
    int*    hist_all = (int*)   alloc((size_t)L2 * 4);
    int*    partials = (int*)   alloc((size_t)256 * 4);
    float*  norm_src = (float*) alloc((size_t)n * 4);
    float*  norm_dst = (float*) alloc((size_t)n * 4);
    int*    row_ptr  = (int*)   alloc((size_t)(n + 1) * 4);
    int*    col      = (int*)   alloc((size_t)E * 4);
    ushort* xb1      = (ushort*)alloc((size_t)n * 128 * 2);
    ushort* xb2      = (ushort*)alloc((size_t)n * 128 * 2);
    char*   scratch  = (char*)  alloc((size_t)12 * E);       // CSR scratch; yb aliases after D6
    ushort* W1f      = (ushort*)alloc((size_t)16384 * 2);
    ushort* W2f      = (ushort*)alloc((size_t)16384 * 2);
    ushort* W3f      = (ushort*)alloc((size_t)8192 * 2);

    char* scr = scratch;
    ushort*        rankD = (ushort*)scr;                 scr += ((size_t)E * 2 + 255) & ~(size_t)255;
    ushort*        rankS = (ushort*)scr;                 scr += ((size_t)E * 2 + 255) & ~(size_t)255;
    unsigned*      packD = (unsigned*)scr;               scr += ((size_t)E * 4 + 255) & ~(size_t)255;
    unsigned char* srcb  = (unsigned char*)scr;
    ushort* yb = (ushort*)scratch;  // reuses dead CSR scratch after D6

    int mmb = (n + 63) / 64;       // mm1 tiles (4 waves x 16 rows)
    int fb  = (n + 63) / 64;       // aggmm blocks (4 waves x 16 nodes)
    int ab  = (n + 3) / 4;

    front_kernel<<<nblk1 + 20, 256, 0, stream>>>(ei, E, nblk1, NB, hist_all,
                                                 rankD, rankS, W1, W2, W3, W1f, W2f, W3f);
    scanA_kernel<<<sb2, 256, 0, stream>>>(hist_all, L2, partials);
    scanB_kernel<<<1, 256, 0, stream>>>(partials, sb2);
    scanC_kernel<<<sb2, 256, 0, stream>>>(hist_all, L2, partials);
    scatter_mm1_kernel<<<nblk1 + mmb, 256, 0, stream>>>(ei, E, nblk1, NB, hist_all,
                                                        rankD, rankS, packD, srcb,
                                                        features, W1f, xb1, n);
    bucket_kernel<<<2 * NB, 256, 0, stream>>>(packD, srcb, hist_all, nblk1, NB, n, E,
                                              row_ptr, col, norm_src, norm_dst);
    aggmm_kernel<1, 0, 8, 1, 0><<<fb, 256, 0, stream>>>(xb1, row_ptr, col, b1,
                                                        norm_dst, norm_src, W2f, xb2, n);
    aggmm_kernel<0, 1, 4, 0, 1><<<fb, 256, 0, stream>>>(xb2, row_ptr, col, b2,
                                                        norm_dst, norm_src, W3f, yb, n);
    agg40_kernel<<<ab, 256, 0, stream>>>(yb, row_ptr, col, norm_dst, b3, (float*)d_out, n);
}

// Round 18
// 163.574 us; speedup vs baseline: 1.2839x; 1.2839x over previous
//
#include <hip/hip_runtime.h>

// GCN 3-layer forward on MI355X.
// CSR build WITHOUT global atomics; all matmuls on MFMA; 9 dispatches:
//   D1: hist_rank + prep_w        D2-4: hierarchical scan
//   D5: scatter_part + mm1 (fp32->bf16 A in-reg) -> xb1
//   D6: bucket -> row_ptr/col/norms
//   D7: FUSED agg(xb1, edge-ns)+act(b1,nd) -> LDS -> MFMA @W2 *ns -> xb2
//   D8: FUSED agg(xb2)+act(b2,nd)*ns -> LDS -> MFMA @W3 -> yb (pad 40->64)
//   D9: agg40 -> out fp32
// aggmm = round-16 structure (4 waves x 4 nodes, quarter-gather, one barrier;
// r17's wave-private variant regressed: 12x shuffle traffic). Gather loop
// unrolled x2 for doubled outstanding loads per lane.

#define EPB 4096
#define SCAN_CHUNK 4096

typedef short v8s __attribute__((ext_vector_type(8)));
typedef float v4f __attribute__((ext_vector_type(4)));

__device__ __forceinline__ ushort f2bf(float f) {
    unsigned u = __float_as_uint(f);
    unsigned r = (u + 0x7fffu + ((u >> 16) & 1u)) >> 16;  // RN-even
    return (ushort)r;
}
__device__ __forceinline__ void unpack2(unsigned w, float& lo, float& hi) {
    lo = __uint_as_float(w << 16);
    hi = __uint_as_float(w & 0xffff0000u);
}

// ---------------- D1: hist_rank + prep_w (fused) ----------------
__global__ __launch_bounds__(256) void front_kernel(const int* __restrict__ ei, int E,
        int nblk1, int NB, int* __restrict__ hist_all,
        ushort* __restrict__ rankD, ushort* __restrict__ rankS,
        const float* __restrict__ W1, const float* __restrict__ W2,
        const float* __restrict__ W3,
        ushort* __restrict__ W1f, ushort* __restrict__ W2f, ushort* __restrict__ W3f) {
    __shared__ int hd[512];
    __shared__ int hs[512];
    int t = threadIdx.x;
    if ((int)blockIdx.x >= nblk1) {
        int idx = ((int)blockIdx.x - nblk1) * 256 + t;
        const float* W; ushort* Wf; int Dout, NF, base;
        if (idx < 2048)      { W = W1; Wf = W1f; Dout = 128; NF = 8; base = idx; }
        else if (idx < 4096) { W = W2; Wf = W2f; Dout = 128; NF = 8; base = idx - 2048; }
        else if (idx < 5120) { W = W3; Wf = W3f; Dout = 40;  NF = 4; base = idx - 4096; }
        else return;
        int lane = base & 63;
        int f = (base >> 6) % NF;
        int ks = base / (64 * NF);
        int c = f * 16 + (lane & 15);
        int kbase = ks * 32 + (lane >> 4) * 8;
        unsigned p[4];
        #pragma unroll
        for (int j = 0; j < 4; ++j) {
            float wlo = (c < Dout) ? W[(size_t)(kbase + 2 * j) * Dout + c] : 0.f;
            float whi = (c < Dout) ? W[(size_t)(kbase + 2 * j + 1) * Dout + c] : 0.f;
            p[j] = (unsigned)f2bf(wlo) | ((unsigned)f2bf(whi) << 16);
        }
        *reinterpret_cast<uint4*>(Wf + (size_t)base * 8) = make_uint4(p[0], p[1], p[2], p[3]);
        return;
    }
    int blk = blockIdx.x;
    for (int i = t; i < 512; i += 256) { hd[i] = 0; hs[i] = 0; }
    __syncthreads();
    int base = blk * EPB;
    #pragma unroll
    for (int j = 0; j < 16; ++j) {
        int e = base + j * 256 + t;
        if (e < E) {
            int s = ei[e], d = ei[E + e];
            rankS[e] = (ushort)atomicAdd(&hs[s >> 8], 1);
            rankD[e] = (ushort)atomicAdd(&hd[d >> 8], 1);
        }
    }
    __syncthreads();
    int L = NB * nblk1;
    for (int b = t; b < NB; b += 256) {
        hist_all[b * nblk1 + blk]     = hd[b];
        hist_all[L + b * nblk1 + blk] = hs[b];
    }
}

// ---------------- scan ----------------
__global__ __launch_bounds__(256) void scanA_kernel(const int* __restrict__ data, int L2,
                                                    int* __restrict__ partials) {
    __shared__ int red[256];
    int t = threadIdx.x;
    int base = blockIdx.x * SCAN_CHUNK;
    int s = 0;
    for (int i = t; i < SCAN_CHUNK; i += 256) {
        int idx = base + i;
        if (idx < L2) s += data[idx];
    }
    red[t] = s;
    __syncthreads();
    for (int off = 128; off > 0; off >>= 1) {
        if (t < off) red[t] += red[t + off];
        __syncthreads();
    }
    if (t == 0) partials[blockIdx.x] = red[0];
}

__global__ __launch_bounds__(256) void scanB_kernel(int* __restrict__ partials, int nparts) {
    __shared__ int s[256];
    int t = threadIdx.x;
    s[t] = (t < nparts) ? partials[t] : 0;
    __syncthreads();
    for (int off = 1; off < 256; off <<= 1) {
        int v = (t >= off) ? s[t - off] : 0;
        __syncthreads();
        s[t] += v;
        __syncthreads();
    }
    if (t < nparts) partials[t] = s[t] - partials[t];
}

__global__ __launch_bounds__(256) void scanC_kernel(int* __restrict__ data, int L2,
                                                    const int* __restrict__ partials) {
    __shared__ int tsum[256];
    int t = threadIdx.x;
    int base = blockIdx.x * SCAN_CHUNK + t * 16;
    int local[16];
    int s = 0;
    #pragma unroll
    for (int i = 0; i < 16; ++i) {
        int idx = base + i;
        int v = (idx < L2) ? data[idx] : 0;
        local[i] = v;
        s += v;
    }
    tsum[t] = s;
    __syncthreads();
    for (int off = 1; off < 256; off <<= 1) {
        int v = (t >= off) ? tsum[t - off] : 0;
        __syncthreads();
        tsum[t] += v;
        __syncthreads();
    }
    int run = partials[blockIdx.x] + (t ? tsum[t - 1] : 0);
    #pragma unroll
    for (int i = 0; i < 16; ++i) {
        int idx = base + i;
        if (idx < L2) {
            data[idx] = run;
            run += local[i];
        }
    }
}

// ---------------- MFMA matmul body (global-A, for mm1) ----------------
template<int NF, int DO_NS, int FP32IN>
__device__ __forceinline__ void mm_body(const void* __restrict__ Xv,
        const ushort* __restrict__ Wf, const float* __restrict__ ns,
        ushort* __restrict__ out, int n, int blk, int wv, int lane) {
    int row0 = (blk * 4 + wv) * 16;
    if (row0 >= n) return;
    int arow = row0 + (lane & 15);
    if (arow >= n) arow = n - 1;
    int kgrp = lane >> 4;
    const v8s* bp = reinterpret_cast<const v8s*>(Wf);
    v4f acc[NF];
    #pragma unroll
    for (int f = 0; f < NF; ++f) acc[f] = (v4f){0.f, 0.f, 0.f, 0.f};
    #pragma unroll
    for (int ks = 0; ks < 4; ++ks) {
        v8s a;
        if (FP32IN) {
            const float* xp = (const float*)Xv + (size_t)arow * 128 + (ks * 4 + kgrp) * 8;
            float4 lo = *reinterpret_cast<const float4*>(xp);
            float4 hi = *reinterpret_cast<const float4*>(xp + 4);
            a[0] = (short)f2bf(lo.x); a[1] = (short)f2bf(lo.y);
            a[2] = (short)f2bf(lo.z); a[3] = (short)f2bf(lo.w);
            a[4] = (short)f2bf(hi.x); a[5] = (short)f2bf(hi.y);
            a[6] = (short)f2bf(hi.z); a[7] = (short)f2bf(hi.w);
        } else {
            const v8s* ap = reinterpret_cast<const v8s*>((const ushort*)Xv + (size_t)arow * 128);
            a = ap[ks * 4 + kgrp];
        }
        #pragma unroll
        for (int f = 0; f < NF; ++f) {
            v8s b = bp[(ks * NF + f) * 64 + lane];
            acc[f] = __builtin_amdgcn_mfma_f32_16x16x32_bf16(a, b, acc[f], 0, 0, 0);
        }
    }
    int rbase = row0 + (lane >> 4) * 4;
    int ccol = lane & 15;
    constexpr int OS = NF * 16;
    #pragma unroll
    for (int r = 0; r < 4; ++r) {
        int gr = rbase + r;
        if (gr < n) {
            float s = DO_NS ? ns[gr] : 1.f;
            #pragma unroll
            for (int f = 0; f < NF; ++f)
                out[(size_t)gr * OS + f * 16 + ccol] = f2bf(s * acc[f][r]);
        }
    }
}

// ---------------- D5: scatter_part + mm1 (fused) ----------------
__global__ __launch_bounds__(256) void scatter_mm1_kernel(const int* __restrict__ ei, int E,
        int nblk1, int NB, const int* __restrict__ hist_all,
        const ushort* __restrict__ rankD, const ushort* __restrict__ rankS,
        unsigned* __restrict__ packD, unsigned char* __restrict__ srcb,
        const float* __restrict__ features, const ushort* __restrict__ W1f,
        ushort* __restrict__ xb, int n) {
    int t = threadIdx.x;
    if ((int)blockIdx.x >= nblk1) {
        int blk = (int)blockIdx.x - nblk1;
        mm_body<8, 0, 1>(features, W1f, nullptr, xb, n, blk, t >> 6, t & 63);
        return;
    }
    int blk = blockIdx.x;
    int base = blk * EPB;
    int L = NB * nblk1;
    #pragma unroll
    for (int j = 0; j < 16; ++j) {
        int e = base + j * 256 + t;
        if (e < E) {
            int s = ei[e], d = ei[E + e];
            int posD = hist_all[(d >> 8) * nblk1 + blk] + (int)rankD[e];
            packD[posD] = ((unsigned)(d & 255) << 24) | (unsigned)s;
            int posS = hist_all[L + (s >> 8) * nblk1 + blk] - E + (int)rankS[e];
            srcb[posS] = (unsigned char)(s & 255);
        }
    }
}

// ---------------- D6: bucket ----------------
__global__ __launch_bounds__(256) void bucket_kernel(const unsigned* __restrict__ packD,
        const unsigned char* __restrict__ srcb, const int* __restrict__ hist_all,
        int nblk1, int NB, int n, int E,
        int* __restrict__ row_ptr, int* __restrict__ col,
        float* __restrict__ norm_src, float* __restrict__ norm_dst) {
    int t = threadIdx.x;
    __shared__ int cnt[256];
    __shared__ int incl[256];
    __shared__ int cur[256];
    if ((int)blockIdx.x < NB) {
        int B = blockIdx.x;
        int s0 = hist_all[B * nblk1];
        int s1 = (B + 1 < NB) ? hist_all[(B + 1) * nblk1] : E;
        cnt[t] = 0;
        __syncthreads();
        for (int i = s0 + t; i < s1; i += 256)
            atomicAdd(&cnt[packD[i] >> 24], 1);
        __syncthreads();
        int v = cnt[t];
        incl[t] = v;
        __syncthreads();
        for (int off = 1; off < 256; off <<= 1) {
            int w = (t >= off) ? incl[t - off] : 0;
            __syncthreads();
            incl[t] += w;
            __syncthreads();
        }
        int excl = incl[t] - v;
        cur[t] = excl;
        int node = B * 256 + t;
        if (node < n) {
            row_ptr[node] = s0 + excl;
            norm_dst[node] = rsqrtf((float)(v > 0 ? v : 1));
        }
        if (B == NB - 1 && t == 0) row_ptr[n] = E;
        __syncthreads();
        for (int i = s0 + t; i < s1; i += 256) {
            unsigned p = packD[i];
            int r = atomicAdd(&cur[p >> 24], 1);
            col[s0 + r] = (int)(p & 0xFFFFFFu);
        }
    } else {
        int B = (int)blockIdx.x - NB;
        int L = NB * nblk1;
        int s0 = hist_all[L + B * nblk1] - E;
        int s1 = (B + 1 < NB) ? (hist_all[L + (B + 1) * nblk1] - E) : E;
        cnt[t] = 0;
        __syncthreads();
        for (int i = s0 + t; i < s1; i += 256)
            atomicAdd(&cnt[srcb[i]], 1);
        __syncthreads();
        int node = B * 256 + t;
        if (node < n) {
            int v = cnt[t];
            norm_src[node] = rsqrtf((float)(v > 0 ? v : 1));
        }
    }
}

// ---------------- D7/D8: FUSED agg + MFMA (round-16 structure) ----------------
// Block = 16 nodes. Wave wv aggregates nodes row0+wv*4..+3 (quarter-gather,
// 2x unrolled: edges j+quarter and j+4+quarter in flight), activation, bf16
// row to LDS [16][136]. Barrier. Wave wv computes frags F=wv*FPW..+FPW-1.
template<int EDGE_NS, int ACT_NS, int NF_TOT, int MM_NS, int PAD40>
__global__ __launch_bounds__(256) void aggmm_kernel(const ushort* __restrict__ xt,
        const int* __restrict__ row_ptr, const int* __restrict__ col,
        const float* __restrict__ bias, const float* __restrict__ norm_dst,
        const float* __restrict__ norm_src, const ushort* __restrict__ Wf,
        ushort* __restrict__ out, int n) {
    __shared__ ushort Xl[16][136];
    int t = threadIdx.x;
    int wv = t >> 6, lane = t & 63;
    int row0 = (int)blockIdx.x * 16;
    int quarter = lane >> 4, l4 = lane & 15;
    for (int i = 0; i < 4; ++i) {
        int vi = row0 + wv * 4 + i;
        int lrow = wv * 4 + i;
        if (vi < n) {
            int start = row_ptr[vi], end = row_ptr[vi + 1];
            float acc[8];
            #pragma unroll
            for (int q = 0; q < 8; ++q) acc[q] = 0.f;
            for (int b = start; b < end; b += 64) {
                int m = end - b; if (m > 64) m = 64;
                int u = 0; float s = 1.f;
                if (lane < m) {
                    u = col[b + lane];
                    if (EDGE_NS) s = norm_src[u];
                }
                for (int j = 0; j < m; j += 8) {
                    int jj0 = j + quarter;
                    int jj1 = j + 4 + quarter;
                    int uu0 = __shfl(u, jj0);
                    int uu1 = __shfl(u, jj1);
                    float ss0 = EDGE_NS ? __shfl(s, jj0) : 1.f;
                    float ss1 = EDGE_NS ? __shfl(s, jj1) : 1.f;
                    float f0, f1;
                    if (jj0 < m) {
                        const uint4 v = *reinterpret_cast<const uint4*>(xt + (size_t)uu0 * 128 + 8 * l4);
                        if (EDGE_NS) {
                            unpack2(v.x, f0, f1); acc[0] = fmaf(ss0, f0, acc[0]); acc[1] = fmaf(ss0, f1, acc[1]);
                            unpack2(v.y, f0, f1); acc[2] = fmaf(ss0, f0, acc[2]); acc[3] = fmaf(ss0, f1, acc[3]);
                            unpack2(v.z, f0, f1); acc[4] = fmaf(ss0, f0, acc[4]); acc[5] = fmaf(ss0, f1, acc[5]);
                            unpack2(v.w, f0, f1); acc[6] = fmaf(ss0, f0, acc[6]); acc[7] = fmaf(ss0, f1, acc[7]);
                        } else {
                            unpack2(v.x, f0, f1); acc[0] += f0; acc[1] += f1;
                            unpack2(v.y, f0, f1); acc[2] += f0; acc[3] += f1;
                            unpack2(v.z, f0, f1); acc[4] += f0; acc[5] += f1;
                            unpack2(v.w, f0, f1); acc[6] += f0; acc[7] += f1;
                        }
                    }
                    if (jj1 < m) {
                        const uint4 v = *reinterpret_cast<const uint4*>(xt + (size_t)uu1 * 128 + 8 * l4);
                        if (EDGE_NS) {
                            unpack2(v.x, f0, f1); acc[0] = fmaf(ss1, f0, acc[0]); acc[1] = fmaf(ss1, f1, acc[1]);
                            unpack2(v.y, f0, f1); acc[2] = fmaf(ss1, f0, acc[2]); acc[3] = fmaf(ss1, f1, acc[3]);
                            unpack2(v.z, f0, f1); acc[4] = fmaf(ss1, f0, acc[4]); acc[5] = fmaf(ss1, f1, acc[5]);
                            unpack2(v.w, f0, f1); acc[6] = fmaf(ss1, f0, acc[6]); acc[7] = fmaf(ss1, f1, acc[7]);
                        } else {
                            unpack2(v.x, f0, f1); acc[0] += f0; acc[1] += f1;
                            unpack2(v.y, f0, f1); acc[2] += f0; acc[3] += f1;
                            unpack2(v.z, f0, f1); acc[4] += f0; acc[5] += f1;
                            unpack2(v.w, f0, f1); acc[6] += f0; acc[7] += f1;
                        }
                    }
                }
            }
            #pragma unroll
            for (int q = 0; q < 8; ++q) {
                acc[q] += __shfl_xor(acc[q], 16);
                acc[q] += __shfl_xor(acc[q], 32);
            }
            if (lane < 16) {
                float nd = norm_dst[vi];
                float sc = ACT_NS ? norm_src[vi] : 1.f;
                const float* bp = bias + 8 * lane;
                unsigned p[4];
                #pragma unroll
                for (int q = 0; q < 4; ++q) {
                    float lo = fmaxf(fmaf(nd, acc[2 * q],     bp[2 * q]),     0.f) * sc;
                    float hi = fmaxf(fmaf(nd, acc[2 * q + 1], bp[2 * q + 1]), 0.f) * sc;
                    p[q] = (unsigned)f2bf(lo) | ((unsigned)f2bf(hi) << 16);
                }
                *reinterpret_cast<uint4*>(&Xl[lrow][8 * lane]) = make_uint4(p[0], p[1], p[2], p[3]);
            }
        } else if (lane < 16) {
            *reinterpret_cast<uint4*>(&Xl[lrow][8 * lane]) = make_uint4(0, 0, 0, 0);
        }
    }
    __syncthreads();
    constexpr int FPW = NF_TOT / 4;
    const v8s* bp = reinterpret_cast<const v8s*>(Wf);
    int kgrp = lane >> 4;
    v4f acc[FPW];
    #pragma unroll
    for (int f = 0; f < FPW; ++f) acc[f] = (v4f){0.f, 0.f, 0.f, 0.f};
    #pragma unroll
    for (int ks = 0; ks < 4; ++ks) {
        v8s a = *reinterpret_cast<const v8s*>(&Xl[lane & 15][(ks * 4 + kgrp) * 8]);
        #pragma unroll
        for (int f = 0; f < FPW; ++f) {
            int F = wv * FPW + f;
            v8s b = bp[(ks * NF_TOT + F) * 64 + lane];
            acc[f] = __builtin_amdgcn_mfma_f32_16x16x32_bf16(a, b, acc[f], 0, 0, 0);
        }
    }
    int rbase = row0 + (lane >> 4) * 4;
    int ccol = lane & 15;
    constexpr int OS = NF_TOT * 16;
    #pragma unroll
    for (int r = 0; r < 4; ++r) {
        int gr = rbase + r;
        if (gr < n) {
            float s = MM_NS ? norm_src[gr] : 1.f;
            #pragma unroll
            for (int f = 0; f < FPW; ++f) {
                int colo = (wv * FPW + f) * 16 + ccol;
                ushort val = f2bf(s * acc[f][r]);
                if (PAD40 && colo >= 40) val = 0;
                out[(size_t)gr * OS + colo] = val;
            }
        }
    }
}

// ---------------- D9: agg40 ----------------
__global__ __launch_bounds__(256) void agg40_kernel(const ushort* __restrict__ yb,
        const int* __restrict__ row_ptr, const int* __restrict__ col,
        const float* __restrict__ norm_dst, const float* __restrict__ b3,
        float* __restrict__ out, int n) {
    int wid  = (blockIdx.x * blockDim.x + threadIdx.x) >> 6;
    int lane = threadIdx.x & 63;
    if (wid >= n) return;
    int start = row_ptr[wid], end = row_ptr[wid + 1];
    int oct = lane >> 3, l8 = lane & 7;
    float acc[8];
    #pragma unroll
    for (int i = 0; i < 8; ++i) acc[i] = 0.f;
    for (int b = start; b < end; b += 64) {
        int m = end - b; if (m > 64) m = 64;
        int u = 0;
        if (lane < m) u = col[b + lane];
        for (int j = 0; j < m; j += 8) {
            int jj = j + oct;
            int uu = __shfl(u, jj);
            if (jj < m) {
                const uint4 v = *reinterpret_cast<const uint4*>(yb + (size_t)uu * 64 + 8 * l8);
                float f0, f1;
                unpack2(v.x, f0, f1); acc[0] += f0; acc[1] += f1;
                unpack2(v.y, f0, f1); acc[2] += f0; acc[3] += f1;
                unpack2(v.z, f0, f1); acc[4] += f0; acc[5] += f1;
                unpack2(v.w, f0, f1); acc[6] += f0; acc[7] += f1;
            }
        }
    }
    #pragma unroll
    for (int i = 0; i < 8; ++i) {
        acc[i] += __shfl_xor(acc[i], 8);
        acc[i] += __shfl_xor(acc[i], 16);
        acc[i] += __shfl_xor(acc[i], 32);
    }
    if (lane < 5) {
        float nd = norm_dst[wid];
        const float* bp = b3 + 8 * lane;
        float* op = out + (size_t)wid * 40 + 8 * lane;
        float4 o0, o1;
        o0.x = fmaf(nd, acc[0], bp[0]); o0.y = fmaf(nd, acc[1], bp[1]);
        o0.z = fmaf(nd, acc[2], bp[2]); o0.w = fmaf(nd, acc[3], bp[3]);
        o1.x = fmaf(nd, acc[4], bp[4]); o1.y = fmaf(nd, acc[5], bp[5]);
        o1.z = fmaf(nd, acc[6], bp[6]); o1.w = fmaf(nd, acc[7], bp[7]);
        *reinterpret_cast<float4*>(op)     = o0;
        *reinterpret_cast<float4*>(op + 4) = o1;
    }
}

extern "C" void kernel_launch(void* const* d_in, const int* in_sizes, int n_in,
                              void* d_out, int out_size, void* d_ws, size_t ws_size,
                              hipStream_t stream) {
    const float* features = (const float*)d_in[0];
    const int*   ei       = (const int*)d_in[1];
    const float* W1 = (const float*)d_in[2];
    const float* b1 = (const float*)d_in[3];
    const float* W2 = (const float*)d_in[4];
    const float* b2 = (const float*)d_in[5];
    const float* W3 = (const float*)d_in[6];
    const float* b3 = (const float*)d_in[7];

    const int n = in_sizes[0] / 128;
    const int E = in_sizes[1] / 2;

    const int nblk1 = (E + EPB - 1) / EPB;
    const int NB    = (n + 255) >> 8;
    const int L     = NB * nblk1;
    const int L2    = 2 * L;
    const int sb2   = (L2 + SCAN_CHUNK - 1) / SCAN_CHUNK;

    char* w = (char*)d_ws;
    auto alloc = [&](size_t bytes) {
        char* p = w;
        w += (bytes + 255) & ~(size_t)255;
        return p;
    };
    int*    hist_all = (int*)   alloc((size_t)L2 * 4);
    int*    partials = (int*)   alloc((size_t)256 * 4);
    float*  norm_src = (float*) alloc((size_t)n * 4);
    float*  norm_dst = (float*) alloc((size_t)n * 4);
    int*    row_ptr  = (int*)   alloc((size_t)(n + 1) * 4);
    int*    col      = (int*)   alloc((size_t)E * 4);
    ushort* xb1      = (ushort*)alloc((size_t)n * 128 * 2);
    ushort* xb2      = (ushort*)alloc((size_t)n * 128 * 2);
    char*   scratch  = (char*)  alloc((size_t)12 * E);       // CSR scratch; yb aliases after D6
    ushort* W1f      = (ushort*)alloc((size_t)16384 * 2);
    ushort* W2f      = (ushort*)alloc((size_t)16384 * 2);
    ushort* W3f      = (ushort*)alloc((size_t)8192 * 2);

    char* scr = scratch;
    ushort*        rankD = (ushort*)scr;                 scr += ((size_t)E * 2 + 255) & ~(size_t)255;
    ushort*        rankS = (ushort*)scr;                 scr += ((size_t)E * 2 + 255) & ~(size_t)255;
    unsigned*      packD = (unsigned*)scr;               scr += ((size_t)E * 4 + 255) & ~(size_t)255;
    unsigned char* srcb  = (unsigned char*)scr;
    ushort* yb = (ushort*)scratch;  // reuses dead CSR scratch after D6

    int mmb = (n + 63) / 64;       // mm1 tiles (4 waves x 16 rows)
    int fb  = (n + 15) / 16;       // fused agg+mm blocks (16 nodes each)
    int ab  = (n + 3) / 4;

    front_kernel<<<nblk1 + 20, 256, 0, stream>>>(ei, E, nblk1, NB, hist_all,
                                                 rankD, rankS, W1, W2, W3, W1f, W2f, W3f);
    scanA_kernel<<<sb2, 256, 0, stream>>>(hist_all, L2, partials);
    scanB_kernel<<<1, 256, 0, stream>>>(partials, sb2);
    scanC_kernel<<<sb2, 256, 0, stream>>>(hist_all, L2, partials);
    scatter_mm1_kernel<<<nblk1 + mmb, 256, 0, stream>>>(ei, E, nblk1, NB, hist_all,
                                                        rankD, rankS, packD, srcb,
                                                        features, W1f, xb1, n);
    bucket_kernel<<<2 * NB, 256, 0, stream>>>(packD, srcb, hist_all, nblk1, NB, n, E,
                                              row_ptr, col, norm_src, norm_dst);
    aggmm_kernel<1, 0, 8, 1, 0><<<fb, 256, 0, stream>>>(xb1, row_ptr, col, b1,
                                                        norm_dst, norm_src, W2f, xb2, n);
    aggmm_kernel<0, 1, 4, 0, 1><<<fb, 256, 0, stream>>>(xb2, row_ptr, col, b2,
                                                        norm_dst, norm_src, W3f, yb, n);
    agg40_kernel<<<ab, 256, 0, stream>>>(yb, row_ptr, col, norm_dst, b3, (float*)d_out, n);
}

// Round 19
// 148.900 us; speedup vs baseline: 1.4105x; 1.0986x over previous
//
#include <hip/hip_runtime.h>

// GCN 3-layer forward on MI355X.
// CSR build WITHOUT global atomics; all matmuls on MFMA; 8 dispatches:
//   D1: hist_rank + prep_w        D2-3: scan (scanB folded into scanC)
//   D4: scatter_part + mm1 -> xb1
//   D5: bucket -> row_ptr/col/norms
//   D6: FUSED agg+act+MFMA@W2 -> xb2   (quarter-per-node gather, 0 shuffles)
//   D7: FUSED agg+act+MFMA@W3 -> yb
//   D8: agg40 (octant-per-node, 0 shuffles) -> out fp32
// Gather v3: 16 lanes own one node (8 dims/lane); col/norm loads are
// same-address broadcasts; no redistribution or reduction shuffles.

#define EPB 4096
#define SCAN_CHUNK 4096

typedef short v8s __attribute__((ext_vector_type(8)));
typedef float v4f __attribute__((ext_vector_type(4)));

__device__ __forceinline__ ushort f2bf(float f) {
    unsigned u = __float_as_uint(f);
    unsigned r = (u + 0x7fffu + ((u >> 16) & 1u)) >> 16;  // RN-even
    return (ushort)r;
}
__device__ __forceinline__ void unpack2(unsigned w, float& lo, float& hi) {
    lo = __uint_as_float(w << 16);
    hi = __uint_as_float(w & 0xffff0000u);
}

// ---------------- D1: hist_rank + prep_w (fused) ----------------
__global__ __launch_bounds__(256) void front_kernel(const int* __restrict__ ei, int E,
        int nblk1, int NB, int* __restrict__ hist_all,
        ushort* __restrict__ rankD, ushort* __restrict__ rankS,
        const float* __restrict__ W1, const float* __restrict__ W2,
        const float* __restrict__ W3,
        ushort* __restrict__ W1f, ushort* __restrict__ W2f, ushort* __restrict__ W3f) {
    __shared__ int hd[512];
    __shared__ int hs[512];
    int t = threadIdx.x;
    if ((int)blockIdx.x >= nblk1) {
        int idx = ((int)blockIdx.x - nblk1) * 256 + t;
        const float* W; ushort* Wf; int Dout, NF, base;
        if (idx < 2048)      { W = W1; Wf = W1f; Dout = 128; NF = 8; base = idx; }
        else if (idx < 4096) { W = W2; Wf = W2f; Dout = 128; NF = 8; base = idx - 2048; }
        else if (idx < 5120) { W = W3; Wf = W3f; Dout = 40;  NF = 4; base = idx - 4096; }
        else return;
        int lane = base & 63;
        int f = (base >> 6) % NF;
        int ks = base / (64 * NF);
        int c = f * 16 + (lane & 15);
        int kbase = ks * 32 + (lane >> 4) * 8;
        unsigned p[4];
        #pragma unroll
        for (int j = 0; j < 4; ++j) {
            float wlo = (c < Dout) ? W[(size_t)(kbase + 2 * j) * Dout + c] : 0.f;
            float whi = (c < Dout) ? W[(size_t)(kbase + 2 * j + 1) * Dout + c] : 0.f;
            p[j] = (unsigned)f2bf(wlo) | ((unsigned)f2bf(whi) << 16);
        }
        *reinterpret_cast<uint4*>(Wf + (size_t)base * 8) = make_uint4(p[0], p[1], p[2], p[3]);
        return;
    }
    int blk = blockIdx.x;
    for (int i = t; i < 512; i += 256) { hd[i] = 0; hs[i] = 0; }
    __syncthreads();
    int base = blk * EPB;
    #pragma unroll
    for (int j = 0; j < 16; ++j) {
        int e = base + j * 256 + t;
        if (e < E) {
            int s = ei[e], d = ei[E + e];
            rankS[e] = (ushort)atomicAdd(&hs[s >> 8], 1);
            rankD[e] = (ushort)atomicAdd(&hd[d >> 8], 1);
        }
    }
    __syncthreads();
    int L = NB * nblk1;
    for (int b = t; b < NB; b += 256) {
        hist_all[b * nblk1 + blk]     = hd[b];
        hist_all[L + b * nblk1 + blk] = hs[b];
    }
}

// ---------------- scan ----------------
__global__ __launch_bounds__(256) void scanA_kernel(const int* __restrict__ data, int L2,
                                                    int* __restrict__ partials) {
    __shared__ int red[256];
    int t = threadIdx.x;
    int base = blockIdx.x * SCAN_CHUNK;
    int s = 0;
    for (int i = t; i < SCAN_CHUNK; i += 256) {
        int idx = base + i;
        if (idx < L2) s += data[idx];
    }
    red[t] = s;
    __syncthreads();
    for (int off = 128; off > 0; off >>= 1) {
        if (t < off) red[t] += red[t + off];
        __syncthreads();
    }
    if (t == 0) partials[blockIdx.x] = red[0];
}

// scanC with scanB folded in: thread 0 serially prefixes partials[0..blk).
__global__ __launch_bounds__(256) void scanC_kernel(int* __restrict__ data, int L2,
                                                    const int* __restrict__ partials) {
    __shared__ int tsum[256];
    __shared__ int baseoff;
    int t = threadIdx.x;
    if (t == 0) {
        int s = 0;
        for (int i = 0; i < (int)blockIdx.x; ++i) s += partials[i];
        baseoff = s;
    }
    int base = blockIdx.x * SCAN_CHUNK + t * 16;
    int local[16];
    int s = 0;
    #pragma unroll
    for (int i = 0; i < 16; ++i) {
        int idx = base + i;
        int v = (idx < L2) ? data[idx] : 0;
        local[i] = v;
        s += v;
    }
    tsum[t] = s;
    __syncthreads();
    for (int off = 1; off < 256; off <<= 1) {
        int v = (t >= off) ? tsum[t - off] : 0;
        __syncthreads();
        tsum[t] += v;
        __syncthreads();
    }
    int run = baseoff + (t ? tsum[t - 1] : 0);
    #pragma unroll
    for (int i = 0; i < 16; ++i) {
        int idx = base + i;
        if (idx < L2) {
            data[idx] = run;
            run += local[i];
        }
    }
}

// ---------------- MFMA matmul body (global-A, for mm1) ----------------
template<int NF, int DO_NS, int FP32IN>
__device__ __forceinline__ void mm_body(const void* __restrict__ Xv,
        const ushort* __restrict__ Wf, const float* __restrict__ ns,
        ushort* __restrict__ out, int n, int blk, int wv, int lane) {
    int row0 = (blk * 4 + wv) * 16;
    if (row0 >= n) return;
    int arow = row0 + (lane & 15);
    if (arow >= n) arow = n - 1;
    int kgrp = lane >> 4;
    const v8s* bp = reinterpret_cast<const v8s*>(Wf);
    v4f acc[NF];
    #pragma unroll
    for (int f = 0; f < NF; ++f) acc[f] = (v4f){0.f, 0.f, 0.f, 0.f};
    #pragma unroll
    for (int ks = 0; ks < 4; ++ks) {
        v8s a;
        if (FP32IN) {
            const float* xp = (const float*)Xv + (size_t)arow * 128 + (ks * 4 + kgrp) * 8;
            float4 lo = *reinterpret_cast<const float4*>(xp);
            float4 hi = *reinterpret_cast<const float4*>(xp + 4);
            a[0] = (short)f2bf(lo.x); a[1] = (short)f2bf(lo.y);
            a[2] = (short)f2bf(lo.z); a[3] = (short)f2bf(lo.w);
            a[4] = (short)f2bf(hi.x); a[5] = (short)f2bf(hi.y);
            a[6] = (short)f2bf(hi.z); a[7] = (short)f2bf(hi.w);
        } else {
            const v8s* ap = reinterpret_cast<const v8s*>((const ushort*)Xv + (size_t)arow * 128);
            a = ap[ks * 4 + kgrp];
        }
        #pragma unroll
        for (int f = 0; f < NF; ++f) {
            v8s b = bp[(ks * NF + f) * 64 + lane];
            acc[f] = __builtin_amdgcn_mfma_f32_16x16x32_bf16(a, b, acc[f], 0, 0, 0);
        }
    }
    int rbase = row0 + (lane >> 4) * 4;
    int ccol = lane & 15;
    constexpr int OS = NF * 16;
    #pragma unroll
    for (int r = 0; r < 4; ++r) {
        int gr = rbase + r;
        if (gr < n) {
            float s = DO_NS ? ns[gr] : 1.f;
            #pragma unroll
            for (int f = 0; f < NF; ++f)
                out[(size_t)gr * OS + f * 16 + ccol] = f2bf(s * acc[f][r]);
        }
    }
}

// ---------------- D4: scatter_part + mm1 (fused) ----------------
__global__ __launch_bounds__(256) void scatter_mm1_kernel(const int* __restrict__ ei, int E,
        int nblk1, int NB, const int* __restrict__ hist_all,
        const ushort* __restrict__ rankD, const ushort* __restrict__ rankS,
        unsigned* __restrict__ packD, unsigned char* __restrict__ srcb,
        const float* __restrict__ features, const ushort* __restrict__ W1f,
        ushort* __restrict__ xb, int n) {
    int t = threadIdx.x;
    if ((int)blockIdx.x >= nblk1) {
        int blk = (int)blockIdx.x - nblk1;
        mm_body<8, 0, 1>(features, W1f, nullptr, xb, n, blk, t >> 6, t & 63);
        return;
    }
    int blk = blockIdx.x;
    int base = blk * EPB;
    int L = NB * nblk1;
    #pragma unroll
    for (int j = 0; j < 16; ++j) {
        int e = base + j * 256 + t;
        if (e < E) {
            int s = ei[e], d = ei[E + e];
            int posD = hist_all[(d >> 8) * nblk1 + blk] + (int)rankD[e];
            packD[posD] = ((unsigned)(d & 255) << 24) | (unsigned)s;
            int posS = hist_all[L + (s >> 8) * nblk1 + blk] - E + (int)rankS[e];
            srcb[posS] = (unsigned char)(s & 255);
        }
    }
}

// ---------------- D5: bucket ----------------
__global__ __launch_bounds__(256) void bucket_kernel(const unsigned* __restrict__ packD,
        const unsigned char* __restrict__ srcb, const int* __restrict__ hist_all,
        int nblk1, int NB, int n, int E,
        int* __restrict__ row_ptr, int* __restrict__ col,
        float* __restrict__ norm_src, float* __restrict__ norm_dst) {
    int t = threadIdx.x;
    __shared__ int cnt[256];
    __shared__ int incl[256];
    __shared__ int cur[256];
    if ((int)blockIdx.x < NB) {
        int B = blockIdx.x;
        int s0 = hist_all[B * nblk1];
        int s1 = (B + 1 < NB) ? hist_all[(B + 1) * nblk1] : E;
        cnt[t] = 0;
        __syncthreads();
        for (int i = s0 + t; i < s1; i += 256)
            atomicAdd(&cnt[packD[i] >> 24], 1);
        __syncthreads();
        int v = cnt[t];
        incl[t] = v;
        __syncthreads();
        for (int off = 1; off < 256; off <<= 1) {
            int w = (t >= off) ? incl[t - off] : 0;
            __syncthreads();
            incl[t] += w;
            __syncthreads();
        }
        int excl = incl[t] - v;
        cur[t] = excl;
        int node = B * 256 + t;
        if (node < n) {
            row_ptr[node] = s0 + excl;
            norm_dst[node] = rsqrtf((float)(v > 0 ? v : 1));
        }
        if (B == NB - 1 && t == 0) row_ptr[n] = E;
        __syncthreads();
        for (int i = s0 + t; i < s1; i += 256) {
            unsigned p = packD[i];
            int r = atomicAdd(&cur[p >> 24], 1);
            col[s0 + r] = (int)(p & 0xFFFFFFu);
        }
    } else {
        int B = (int)blockIdx.x - NB;
        int L = NB * nblk1;
        int s0 = hist_all[L + B * nblk1] - E;
        int s1 = (B + 1 < NB) ? (hist_all[L + (B + 1) * nblk1] - E) : E;
        cnt[t] = 0;
        __syncthreads();
        for (int i = s0 + t; i < s1; i += 256)
            atomicAdd(&cnt[srcb[i]], 1);
        __syncthreads();
        int node = B * 256 + t;
        if (node < n) {
            int v = cnt[t];
            norm_src[node] = rsqrtf((float)(v > 0 ? v : 1));
        }
    }
}

// ---------------- D6/D7: FUSED agg + MFMA, quarter-per-node gather ----------------
// Block = 16 nodes. Quarter q of wave wv owns node row0+wv*4+q entirely:
// 16 lanes x 8 dims, 16B row-chunk per lane per edge; col/norm_src loads are
// same-address broadcasts within the quarter; 2-deep edge unroll; no shuffles.
// Activation per-lane, bf16 row -> LDS [16][136]. Barrier. MFMA as before.
template<int EDGE_NS, int ACT_NS, int NF_TOT, int MM_NS, int PAD40>
__global__ __launch_bounds__(256) void aggmm_kernel(const ushort* __restrict__ xt,
        const int* __restrict__ row_ptr, const int* __restrict__ col,
        const float* __restrict__ bias, const float* __restrict__ norm_dst,
        const float* __restrict__ norm_src, const ushort* __restrict__ Wf,
        ushort* __restrict__ out, int n) {
    __shared__ ushort Xl[16][136];
    int t = threadIdx.x;
    int wv = t >> 6, lane = t & 63;
    int row0 = (int)blockIdx.x * 16;
    int quarter = lane >> 4, l4 = lane & 15;
    int vi = row0 + wv * 4 + quarter;
    int lrow = wv * 4 + quarter;
    if (vi < n) {
        int start = row_ptr[vi], end = row_ptr[vi + 1];
        float a0[8], a1[8];
        #pragma unroll
        for (int q = 0; q < 8; ++q) { a0[q] = 0.f; a1[q] = 0.f; }
        int e = start;
        for (; e + 2 <= end; e += 2) {
            int u0 = col[e], u1 = col[e + 1];
            float s0 = EDGE_NS ? norm_src[u0] : 1.f;
            float s1 = EDGE_NS ? norm_src[u1] : 1.f;
            const uint4 v0 = *reinterpret_cast<const uint4*>(xt + (size_t)u0 * 128 + 8 * l4);
            const uint4 v1 = *reinterpret_cast<const uint4*>(xt + (size_t)u1 * 128 + 8 * l4);
            float f0, f1;
            if (EDGE_NS) {
                unpack2(v0.x, f0, f1); a0[0] = fmaf(s0, f0, a0[0]); a0[1] = fmaf(s0, f1, a0[1]);
                unpack2(v0.y, f0, f1); a0[2] = fmaf(s0, f0, a0[2]); a0[3] = fmaf(s0, f1, a0[3]);
                unpack2(v0.z, f0, f1); a0[4] = fmaf(s0, f0, a0[4]); a0[5] = fmaf(s0, f1, a0[5]);
                unpack2(v0.w, f0, f1); a0[6] = fmaf(s0, f0, a0[6]); a0[7] = fmaf(s0, f1, a0[7]);
                unpack2(v1.x, f0, f1); a1[0] = fmaf(s1, f0, a1[0]); a1[1] = fmaf(s1, f1, a1[1]);
                unpack2(v1.y, f0, f1); a1[2] = fmaf(s1, f0, a1[2]); a1[3] = fmaf(s1, f1, a1[3]);
                unpack2(v1.z, f0, f1); a1[4] = fmaf(s1, f0, a1[4]); a1[5] = fmaf(s1, f1, a1[5]);
                unpack2(v1.w, f0, f1); a1[6] = fmaf(s1, f0, a1[6]); a1[7] = fmaf(s1, f1, a1[7]);
            } else {
                unpack2(v0.x, f0, f1); a0[0] += f0; a0[1] += f1;
                unpack2(v0.y, f0, f1); a0[2] += f0; a0[3] += f1;
                unpack2(v0.z, f0, f1); a0[4] += f0; a0[5] += f1;
                unpack2(v0.w, f0, f1); a0[6] += f0; a0[7] += f1;
                unpack2(v1.x, f0, f1); a1[0] += f0; a1[1] += f1;
                unpack2(v1.y, f0, f1); a1[2] += f0; a1[3] += f1;
                unpack2(v1.z, f0, f1); a1[4] += f0; a1[5] += f1;
                unpack2(v1.w, f0, f1); a1[6] += f0; a1[7] += f1;
            }
        }
        if (e < end) {
            int u0 = col[e];
            float s0 = EDGE_NS ? norm_src[u0] : 1.f;
            const uint4 v0 = *reinterpret_cast<const uint4*>(xt + (size_t)u0 * 128 + 8 * l4);
            float f0, f1;
            if (EDGE_NS) {
                unpack2(v0.x, f0, f1); a0[0] = fmaf(s0, f0, a0[0]); a0[1] = fmaf(s0, f1, a0[1]);
                unpack2(v0.y, f0, f1); a0[2] = fmaf(s0, f0, a0[2]); a0[3] = fmaf(s0, f1, a0[3]);
                unpack2(v0.z, f0, f1); a0[4] = fmaf(s0, f0, a0[4]); a0[5] = fmaf(s0, f1, a0[5]);
                unpack2(v0.w, f0, f1); a0[6] = fmaf(s0, f0, a0[6]); a0[7] = fmaf(s0, f1, a0[7]);
            } else {
                unpack2(v0.x, f0, f1); a0[0] += f0; a0[1] += f1;
                unpack2(v0.y, f0, f1); a0[2] += f0; a0[3] += f1;
                unpack2(v0.z, f0, f1); a0[4] += f0; a0[5] += f1;
                unpack2(v0.w, f0, f1); a0[6] += f0; a0[7] += f1;
            }
        }
        float nd = norm_dst[vi];
        float sc = ACT_NS ? norm_src[vi] : 1.f;
        const float* bp = bias + 8 * l4;
        unsigned p[4];
        #pragma unroll
        for (int q = 0; q < 4; ++q) {
            float lo = fmaxf(fmaf(nd, a0[2 * q]     + a1[2 * q],     bp[2 * q]),     0.f) * sc;
            float hi = fmaxf(fmaf(nd, a0[2 * q + 1] + a1[2 * q + 1], bp[2 * q + 1]), 0.f) * sc;
            p[q] = (unsigned)f2bf(lo) | ((unsigned)f2bf(hi) << 16);
        }
        *reinterpret_cast<uint4*>(&Xl[lrow][16 * l4 / 2]) = make_uint4(p[0], p[1], p[2], p[3]);
    } else {
        *reinterpret_cast<uint4*>(&Xl[lrow][8 * l4]) = make_uint4(0, 0, 0, 0);
    }
    __syncthreads();
    constexpr int FPW = NF_TOT / 4;
    const v8s* bp2 = reinterpret_cast<const v8s*>(Wf);
    int kgrp = lane >> 4;
    v4f acc[FPW];
    #pragma unroll
    for (int f = 0; f < FPW; ++f) acc[f] = (v4f){0.f, 0.f, 0.f, 0.f};
    #pragma unroll
    for (int ks = 0; ks < 4; ++ks) {
        v8s a = *reinterpret_cast<const v8s*>(&Xl[lane & 15][(ks * 4 + kgrp) * 8]);
        #pragma unroll
        for (int f = 0; f < FPW; ++f) {
            int F = wv * FPW + f;
            v8s b = bp2[(ks * NF_TOT + F) * 64 + lane];
            acc[f] = __builtin_amdgcn_mfma_f32_16x16x32_bf16(a, b, acc[f], 0, 0, 0);
        }
    }
    int rbase = row0 + (lane >> 4) * 4;
    int ccol = lane & 15;
    constexpr int OS = NF_TOT * 16;
    #pragma unroll
    for (int r = 0; r < 4; ++r) {
        int gr = rbase + r;
        if (gr < n) {
            float s = MM_NS ? norm_src[gr] : 1.f;
            #pragma unroll
            for (int f = 0; f < FPW; ++f) {
                int colo = (wv * FPW + f) * 16 + ccol;
                ushort val = f2bf(s * acc[f][r]);
                if (PAD40 && colo >= 40) val = 0;
                out[(size_t)gr * OS + colo] = val;
            }
        }
    }
}

// ---------------- D8: agg40, octant-per-node (0 shuffles) ----------------
// Octant o of wave wv owns node blockIdx*32 + wv*8 + o; 8 lanes x 8 dims
// (16B/lane); col loads same-address per octant; 2-deep unroll.
__global__ __launch_bounds__(256) void agg40_kernel(const ushort* __restrict__ yb,
        const int* __restrict__ row_ptr, const int* __restrict__ col,
        const float* __restrict__ norm_dst, const float* __restrict__ b3,
        float* __restrict__ out, int n) {
    int t = threadIdx.x;
    int wv = t >> 6, lane = t & 63;
    int oct = lane >> 3, l8 = lane & 7;
    int vi = (int)blockIdx.x * 32 + wv * 8 + oct;
    if (vi >= n) return;
    int start = row_ptr[vi], end = row_ptr[vi + 1];
    float a0[8], a1[8];
    #pragma unroll
    for (int i = 0; i < 8; ++i) { a0[i] = 0.f; a1[i] = 0.f; }
    int e = start;
    for (; e + 2 <= end; e += 2) {
        int u0 = col[e], u1 = col[e + 1];
        const uint4 v0 = *reinterpret_cast<const uint4*>(yb + (size_t)u0 * 64 + 8 * l8);
        const uint4 v1 = *reinterpret_cast<const uint4*>(yb + (size_t)u1 * 64 + 8 * l8);
        float f0, f1;
        unpack2(v0.x, f0, f1); a0[0] += f0; a0[1] += f1;
        unpack2(v0.y, f0, f1); a0[2] += f0; a0[3] += f1;
        unpack2(v0.z, f0, f1); a0[4] += f0; a0[5] += f1;
        unpack2(v0.w, f0, f1); a0[6] += f0; a0[7] += f1;
        unpack2(v1.x, f0, f1); a1[0] += f0; a1[1] += f1;
        unpack2(v1.y, f0, f1); a1[2] += f0; a1[3] += f1;
        unpack2(v1.z, f0, f1); a1[4] += f0; a1[5] += f1;
        unpack2(v1.w, f0, f1); a1[6] += f0; a1[7] += f1;
    }
    if (e < end) {
        int u0 = col[e];
        const uint4 v0 = *reinterpret_cast<const uint4*>(yb + (size_t)u0 * 64 + 8 * l8);
        float f0, f1;
        unpack2(v0.x, f0, f1); a0[0] += f0; a0[1] += f1;
        unpack2(v0.y, f0, f1); a0[2] += f0; a0[3] += f1;
        unpack2(v0.z, f0, f1); a0[4] += f0; a0[5] += f1;
        unpack2(v0.w, f0, f1); a0[6] += f0; a0[7] += f1;
    }
    if (l8 < 5) {
        float nd = norm_dst[vi];
        const float* bp = b3 + 8 * l8;
        float* op = out + (size_t)vi * 40 + 8 * l8;
        float4 o0, o1;
        o0.x = fmaf(nd, a0[0] + a1[0], bp[0]); o0.y = fmaf(nd, a0[1] + a1[1], bp[1]);
        o0.z = fmaf(nd, a0[2] + a1[2], bp[2]); o0.w = fmaf(nd, a0[3] + a1[3], bp[3]);
        o1.x = fmaf(nd, a0[4] + a1[4], bp[4]); o1.y = fmaf(nd, a0[5] + a1[5], bp[5]);
        o1.z = fmaf(nd, a0[6] + a1[6], bp[6]); o1.w = fmaf(nd, a0[7] + a1[7], bp[7]);
        *reinterpret_cast<float4*>(op)     = o0;
        *reinterpret_cast<float4*>(op + 4) = o1;
    }
}

extern "C" void kernel_launch(void* const* d_in, const int* in_sizes, int n_in,
                              void* d_out, int out_size, void* d_ws, size_t ws_size,
                              hipStream_t stream) {
    const float* features = (const float*)d_in[0];
    const int*   ei       = (const int*)d_in[1];
    const float* W1 = (const float*)d_in[2];
    const float* b1 = (const float*)d_in[3];
    const float* W2 = (const float*)d_in[4];
    const float* b2 = (const float*)d_in[5];
    const float* W3 = (const float*)d_in[6];
    const float* b3 = (const float*)d_in[7];

    const int n = in_sizes[0] / 128;
    const int E = in_sizes[1] / 2;

    const int nblk1 = (E + EPB - 1) / EPB;
    const int NB    = (n + 255) >> 8;
    const int L     = NB * nblk1;
    const int L2    = 2 * L;
    const int sb2   = (L2 + SCAN_CHUNK - 1) / SCAN_CHUNK;

    char* w = (char*)d_ws;
    auto alloc = [&](size_t bytes) {
        char* p = w;
        w += (bytes + 255) & ~(size_t)255;
        return p;
    };
    int*    hist_all = (int*)   alloc((size_t)L2 * 4);
    int*    partials = (int*)   alloc((size_t)256 * 4);
    float*  norm_src = (float*) alloc((size_t)n * 4);
    float*  norm_dst = (float*) alloc((size_t)n * 4);
    int*    row_ptr  = (int*)   alloc((size_t)(n + 1) * 4);
    int*    col      = (int*)   alloc((size_t)E * 4);
    ushort* xb1      = (ushort*)alloc((size_t)n * 128 * 2);
    ushort* xb2      = (ushort*)alloc((size_t)n * 128 * 2);
    char*   scratch  = (char*)  alloc((size_t)12 * E);       // CSR scratch; yb aliases after D5
    ushort* W1f      = (ushort*)alloc((size_t)16384 * 2);
    ushort* W2f      = (ushort*)alloc((size_t)16384 * 2);
    ushort* W3f      = (ushort*)alloc((size_t)8192 * 2);

    char* scr = scratch;
    ushort*        rankD = (ushort*)scr;                 scr += ((size_t)E * 2 + 255) & ~(size_t)255;
    ushort*        rankS = (ushort*)scr;                 scr += ((size_t)E * 2 + 255) & ~(size_t)255;
    unsigned*      packD = (unsigned*)scr;               scr += ((size_t)E * 4 + 255) & ~(size_t)255;
    unsigned char* srcb  = (unsigned char*)scr;
    ushort* yb = (ushort*)scratch;  // reuses dead CSR scratch after D5

    int mmb  = (n + 63) / 64;      // mm1 tiles (4 waves x 16 rows)
    int fb   = (n + 15) / 16;      // fused agg+mm blocks (16 nodes each)
    int ab40 = (n + 31) / 32;      // agg40 blocks (32 nodes each)

    front_kernel<<<nblk1 + 20, 256, 0, stream>>>(ei, E, nblk1, NB, hist_all,
                                                 rankD, rankS, W1, W2, W3, W1f, W2f, W3f);
    scanA_kernel<<<sb2, 256, 0, stream>>>(hist_all, L2, partials);
    scanC_kernel<<<sb2, 256, 0, stream>>>(hist_all, L2, partials);
    scatter_mm1_kernel<<<nblk1 + mmb, 256, 0, stream>>>(ei, E, nblk1, NB, hist_all,
                                                        rankD, rankS, packD, srcb,
                                                        features, W1f, xb1, n);
    bucket_kernel<<<2 * NB, 256, 0, stream>>>(packD, srcb, hist_all, nblk1, NB, n, E,
                                              row_ptr, col, norm_src, norm_dst);
    aggmm_kernel<1, 0, 8, 1, 0><<<fb, 256, 0, stream>>>(xb1, row_ptr, col, b1,
                                                        norm_dst, norm_src, W2f, xb2, n);
    aggmm_kernel<0, 1, 4, 0, 1><<<fb, 256, 0, stream>>>(xb2, row_ptr, col, b2,
                                                        norm_dst, norm_src, W3f, yb, n);
    agg40_kernel<<<ab40, 256, 0, stream>>>(yb, row_ptr, col, norm_dst, b3, (float*)d_out, n);
}

// Round 20
// 148.640 us; speedup vs baseline: 1.4129x; 1.0017x over previous
//
#include <hip/hip_runtime.h>

// GCN 3-layer forward on MI355X.
// CSR build WITHOUT global atomics; all matmuls on MFMA; 8 dispatches:
//   D1: hist_rank + prep_w        D2-3: scan (scanB folded into scanC)
//   D4: scatter_part + mm1 -> xb1
//   D5: bucket -> row_ptr/col/norms
//   D6: FUSED agg+act+MFMA@W2 -> xb2   (quarter-per-node gather, 0 shuffles)
//   D7: FUSED agg+act+MFMA@W3 -> yb    (PACKED 80-B rows, no padding)
//   D8: agg40 (octant-per-node, 5x16B loads) -> out fp32
// Aggregations run at the measured ~6.3 TB/s random-gather ceiling.

#define EPB 4096
#define SCAN_CHUNK 4096

typedef short v8s __attribute__((ext_vector_type(8)));
typedef float v4f __attribute__((ext_vector_type(4)));

__device__ __forceinline__ ushort f2bf(float f) {
    unsigned u = __float_as_uint(f);
    unsigned r = (u + 0x7fffu + ((u >> 16) & 1u)) >> 16;  // RN-even
    return (ushort)r;
}
__device__ __forceinline__ void unpack2(unsigned w, float& lo, float& hi) {
    lo = __uint_as_float(w << 16);
    hi = __uint_as_float(w & 0xffff0000u);
}

// ---------------- D1: hist_rank + prep_w (fused) ----------------
__global__ __launch_bounds__(256) void front_kernel(const int* __restrict__ ei, int E,
        int nblk1, int NB, int* __restrict__ hist_all,
        ushort* __restrict__ rankD, ushort* __restrict__ rankS,
        const float* __restrict__ W1, const float* __restrict__ W2,
        const float* __restrict__ W3,
        ushort* __restrict__ W1f, ushort* __restrict__ W2f, ushort* __restrict__ W3f) {
    __shared__ int hd[512];
    __shared__ int hs[512];
    int t = threadIdx.x;
    if ((int)blockIdx.x >= nblk1) {
        int idx = ((int)blockIdx.x - nblk1) * 256 + t;
        const float* W; ushort* Wf; int Dout, NF, base;
        if (idx < 2048)      { W = W1; Wf = W1f; Dout = 128; NF = 8; base = idx; }
        else if (idx < 4096) { W = W2; Wf = W2f; Dout = 128; NF = 8; base = idx - 2048; }
        else if (idx < 5120) { W = W3; Wf = W3f; Dout = 40;  NF = 4; base = idx - 4096; }
        else return;
        int lane = base & 63;
        int f = (base >> 6) % NF;
        int ks = base / (64 * NF);
        int c = f * 16 + (lane & 15);
        int kbase = ks * 32 + (lane >> 4) * 8;
        unsigned p[4];
        #pragma unroll
        for (int j = 0; j < 4; ++j) {
            float wlo = (c < Dout) ? W[(size_t)(kbase + 2 * j) * Dout + c] : 0.f;
            float whi = (c < Dout) ? W[(size_t)(kbase + 2 * j + 1) * Dout + c] : 0.f;
            p[j] = (unsigned)f2bf(wlo) | ((unsigned)f2bf(whi) << 16);
        }
        *reinterpret_cast<uint4*>(Wf + (size_t)base * 8) = make_uint4(p[0], p[1], p[2], p[3]);
        return;
    }
    int blk = blockIdx.x;
    for (int i = t; i < 512; i += 256) { hd[i] = 0; hs[i] = 0; }
    __syncthreads();
    int base = blk * EPB;
    #pragma unroll
    for (int j = 0; j < 16; ++j) {
        int e = base + j * 256 + t;
        if (e < E) {
            int s = ei[e], d = ei[E + e];
            rankS[e] = (ushort)atomicAdd(&hs[s >> 8], 1);
            rankD[e] = (ushort)atomicAdd(&hd[d >> 8], 1);
        }
    }
    __syncthreads();
    int L = NB * nblk1;
    for (int b = t; b < NB; b += 256) {
        hist_all[b * nblk1 + blk]     = hd[b];
        hist_all[L + b * nblk1 + blk] = hs[b];
    }
}

// ---------------- scan ----------------
__global__ __launch_bounds__(256) void scanA_kernel(const int* __restrict__ data, int L2,
                                                    int* __restrict__ partials) {
    __shared__ int red[256];
    int t = threadIdx.x;
    int base = blockIdx.x * SCAN_CHUNK;
    int s = 0;
    for (int i = t; i < SCAN_CHUNK; i += 256) {
        int idx = base + i;
        if (idx < L2) s += data[idx];
    }
    red[t] = s;
    __syncthreads();
    for (int off = 128; off > 0; off >>= 1) {
        if (t < off) red[t] += red[t + off];
        __syncthreads();
    }
    if (t == 0) partials[blockIdx.x] = red[0];
}

// scanC with scanB folded in: thread 0 serially prefixes partials[0..blk).
__global__ __launch_bounds__(256) void scanC_kernel(int* __restrict__ data, int L2,
                                                    const int* __restrict__ partials) {
    __shared__ int tsum[256];
    __shared__ int baseoff;
    int t = threadIdx.x;
    if (t == 0) {
        int s = 0;
        for (int i = 0; i < (int)blockIdx.x; ++i) s += partials[i];
        baseoff = s;
    }
    int base = blockIdx.x * SCAN_CHUNK + t * 16;
    int local[16];
    int s = 0;
    #pragma unroll
    for (int i = 0; i < 16; ++i) {
        int idx = base + i;
        int v = (idx < L2) ? data[idx] : 0;
        local[i] = v;
        s += v;
    }
    tsum[t] = s;
    __syncthreads();
    for (int off = 1; off < 256; off <<= 1) {
        int v = (t >= off) ? tsum[t - off] : 0;
        __syncthreads();
        tsum[t] += v;
        __syncthreads();
    }
    int run = baseoff + (t ? tsum[t - 1] : 0);
    #pragma unroll
    for (int i = 0; i < 16; ++i) {
        int idx = base + i;
        if (idx < L2) {
            data[idx] = run;
            run += local[i];
        }
    }
}

// ---------------- MFMA matmul body (global-A, for mm1) ----------------
template<int NF, int DO_NS, int FP32IN>
__device__ __forceinline__ void mm_body(const void* __restrict__ Xv,
        const ushort* __restrict__ Wf, const float* __restrict__ ns,
        ushort* __restrict__ out, int n, int blk, int wv, int lane) {
    int row0 = (blk * 4 + wv) * 16;
    if (row0 >= n) return;
    int arow = row0 + (lane & 15);
    if (arow >= n) arow = n - 1;
    int kgrp = lane >> 4;
    const v8s* bp = reinterpret_cast<const v8s*>(Wf);
    v4f acc[NF];
    #pragma unroll
    for (int f = 0; f < NF; ++f) acc[f] = (v4f){0.f, 0.f, 0.f, 0.f};
    #pragma unroll
    for (int ks = 0; ks < 4; ++ks) {
        v8s a;
        if (FP32IN) {
            const float* xp = (const float*)Xv + (size_t)arow * 128 + (ks * 4 + kgrp) * 8;
            float4 lo = *reinterpret_cast<const float4*>(xp);
            float4 hi = *reinterpret_cast<const float4*>(xp + 4);
            a[0] = (short)f2bf(lo.x); a[1] = (short)f2bf(lo.y);
            a[2] = (short)f2bf(lo.z); a[3] = (short)f2bf(lo.w);
            a[4] = (short)f2bf(hi.x); a[5] = (short)f2bf(hi.y);
            a[6] = (short)f2bf(hi.z); a[7] = (short)f2bf(hi.w);
        } else {
            const v8s* ap = reinterpret_cast<const v8s*>((const ushort*)Xv + (size_t)arow * 128);
            a = ap[ks * 4 + kgrp];
        }
        #pragma unroll
        for (int f = 0; f < NF; ++f) {
            v8s b = bp[(ks * NF + f) * 64 + lane];
            acc[f] = __builtin_amdgcn_mfma_f32_16x16x32_bf16(a, b, acc[f], 0, 0, 0);
        }
    }
    int rbase = row0 + (lane >> 4) * 4;
    int ccol = lane & 15;
    constexpr int OS = NF * 16;
    #pragma unroll
    for (int r = 0; r < 4; ++r) {
        int gr = rbase + r;
        if (gr < n) {
            float s = DO_NS ? ns[gr] : 1.f;
            #pragma unroll
            for (int f = 0; f < NF; ++f)
                out[(size_t)gr * OS + f * 16 + ccol] = f2bf(s * acc[f][r]);
        }
    }
}

// ---------------- D4: scatter_part + mm1 (fused) ----------------
__global__ __launch_bounds__(256) void scatter_mm1_kernel(const int* __restrict__ ei, int E,
        int nblk1, int NB, const int* __restrict__ hist_all,
        const ushort* __restrict__ rankD, const ushort* __restrict__ rankS,
        unsigned* __restrict__ packD, unsigned char* __restrict__ srcb,
        const float* __restrict__ features, const ushort* __restrict__ W1f,
        ushort* __restrict__ xb, int n) {
    int t = threadIdx.x;
    if ((int)blockIdx.x >= nblk1) {
        int blk = (int)blockIdx.x - nblk1;
        mm_body<8, 0, 1>(features, W1f, nullptr, xb, n, blk, t >> 6, t & 63);
        return;
    }
    int blk = blockIdx.x;
    int base = blk * EPB;
    int L = NB * nblk1;
    #pragma unroll
    for (int j = 0; j < 16; ++j) {
        int e = base + j * 256 + t;
        if (e < E) {
            int s = ei[e], d = ei[E + e];
            int posD = hist_all[(d >> 8) * nblk1 + blk] + (int)rankD[e];
            packD[posD] = ((unsigned)(d & 255) << 24) | (unsigned)s;
            int posS = hist_all[L + (s >> 8) * nblk1 + blk] - E + (int)rankS[e];
            srcb[posS] = (unsigned char)(s & 255);
        }
    }
}

// ---------------- D5: bucket ----------------
__global__ __launch_bounds__(256) void bucket_kernel(const unsigned* __restrict__ packD,
        const unsigned char* __restrict__ srcb, const int* __restrict__ hist_all,
        int nblk1, int NB, int n, int E,
        int* __restrict__ row_ptr, int* __restrict__ col,
        float* __restrict__ norm_src, float* __restrict__ norm_dst) {
    int t = threadIdx.x;
    __shared__ int cnt[256];
    __shared__ int incl[256];
    __shared__ int cur[256];
    if ((int)blockIdx.x < NB) {
        int B = blockIdx.x;
        int s0 = hist_all[B * nblk1];
        int s1 = (B + 1 < NB) ? hist_all[(B + 1) * nblk1] : E;
        cnt[t] = 0;
        __syncthreads();
        for (int i = s0 + t; i < s1; i += 256)
            atomicAdd(&cnt[packD[i] >> 24], 1);
        __syncthreads();
        int v = cnt[t];
        incl[t] = v;
        __syncthreads();
        for (int off = 1; off < 256; off <<= 1) {
            int w = (t >= off) ? incl[t - off] : 0;
            __syncthreads();
            incl[t] += w;
            __syncthreads();
        }
        int excl = incl[t] - v;
        cur[t] = excl;
        int node = B * 256 + t;
        if (node < n) {
            row_ptr[node] = s0 + excl;
            norm_dst[node] = rsqrtf((float)(v > 0 ? v : 1));
        }
        if (B == NB - 1 && t == 0) row_ptr[n] = E;
        __syncthreads();
        for (int i = s0 + t; i < s1; i += 256) {
            unsigned p = packD[i];
            int r = atomicAdd(&cur[p >> 24], 1);
            col[s0 + r] = (int)(p & 0xFFFFFFu);
        }
    } else {
        int B = (int)blockIdx.x - NB;
        int L = NB * nblk1;
        int s0 = hist_all[L + B * nblk1] - E;
        int s1 = (B + 1 < NB) ? (hist_all[L + (B + 1) * nblk1] - E) : E;
        cnt[t] = 0;
        __syncthreads();
        for (int i = s0 + t; i < s1; i += 256)
            atomicAdd(&cnt[srcb[i]], 1);
        __syncthreads();
        int node = B * 256 + t;
        if (node < n) {
            int v = cnt[t];
            norm_src[node] = rsqrtf((float)(v > 0 ? v : 1));
        }
    }
}

// ---------------- D6/D7: FUSED agg + MFMA, quarter-per-node gather ----------------
// Block = 16 nodes. Quarter q of wave wv owns node row0+wv*4+q entirely:
// 16 lanes x 8 dims, 16B row-chunk per lane per edge; col/norm_src loads are
// same-address broadcasts within the quarter; 2-deep edge unroll; no shuffles.
// Activation per-lane, bf16 row -> LDS [16][136]. Barrier. MFMA.
// OUT40: epilogue writes packed 40-col rows (stride 40), colo<40 only.
template<int EDGE_NS, int ACT_NS, int NF_TOT, int MM_NS, int OUT40>
__global__ __launch_bounds__(256) void aggmm_kernel(const ushort* __restrict__ xt,
        const int* __restrict__ row_ptr, const int* __restrict__ col,
        const float* __restrict__ bias, const float* __restrict__ norm_dst,
        const float* __restrict__ norm_src, const ushort* __restrict__ Wf,
        ushort* __restrict__ out, int n) {
    __shared__ ushort Xl[16][136];
    int t = threadIdx.x;
    int wv = t >> 6, lane = t & 63;
    int row0 = (int)blockIdx.x * 16;
    int quarter = lane >> 4, l4 = lane & 15;
    int vi = row0 + wv * 4 + quarter;
    int lrow = wv * 4 + quarter;
    if (vi < n) {
        int start = row_ptr[vi], end = row_ptr[vi + 1];
        float a0[8], a1[8];
        #pragma unroll
        for (int q = 0; q < 8; ++q) { a0[q] = 0.f; a1[q] = 0.f; }
        int e = start;
        for (; e + 2 <= end; e += 2) {
            int u0 = col[e], u1 = col[e + 1];
            float s0 = EDGE_NS ? norm_src[u0] : 1.f;
            float s1 = EDGE_NS ? norm_src[u1] : 1.f;
            const uint4 v0 = *reinterpret_cast<const uint4*>(xt + (size_t)u0 * 128 + 8 * l4);
            const uint4 v1 = *reinterpret_cast<const uint4*>(xt + (size_t)u1 * 128 + 8 * l4);
            float f0, f1;
            if (EDGE_NS) {
                unpack2(v0.x, f0, f1); a0[0] = fmaf(s0, f0, a0[0]); a0[1] = fmaf(s0, f1, a0[1]);
                unpack2(v0.y, f0, f1); a0[2] = fmaf(s0, f0, a0[2]); a0[3] = fmaf(s0, f1, a0[3]);
                unpack2(v0.z, f0, f1); a0[4] = fmaf(s0, f0, a0[4]); a0[5] = fmaf(s0, f1, a0[5]);
                unpack2(v0.w, f0, f1); a0[6] = fmaf(s0, f0, a0[6]); a0[7] = fmaf(s0, f1, a0[7]);
                unpack2(v1.x, f0, f1); a1[0] = fmaf(s1, f0, a1[0]); a1[1] = fmaf(s1, f1, a1[1]);
                unpack2(v1.y, f0, f1); a1[2] = fmaf(s1, f0, a1[2]); a1[3] = fmaf(s1, f1, a1[3]);
                unpack2(v1.z, f0, f1); a1[4] = fmaf(s1, f0, a1[4]); a1[5] = fmaf(s1, f1, a1[5]);
                unpack2(v1.w, f0, f1); a1[6] = fmaf(s1, f0, a1[6]); a1[7] = fmaf(s1, f1, a1[7]);
            } else {
                unpack2(v0.x, f0, f1); a0[0] += f0; a0[1] += f1;
                unpack2(v0.y, f0, f1); a0[2] += f0; a0[3] += f1;
                unpack2(v0.z, f0, f1); a0[4] += f0; a0[5] += f1;
                unpack2(v0.w, f0, f1); a0[6] += f0; a0[7] += f1;
                unpack2(v1.x, f0, f1); a1[0] += f0; a1[1] += f1;
                unpack2(v1.y, f0, f1); a1[2] += f0; a1[3] += f1;
                unpack2(v1.z, f0, f1); a1[4] += f0; a1[5] += f1;
                unpack2(v1.w, f0, f1); a1[6] += f0; a1[7] += f1;
            }
        }
        if (e < end) {
            int u0 = col[e];
            float s0 = EDGE_NS ? norm_src[u0] : 1.f;
            const uint4 v0 = *reinterpret_cast<const uint4*>(xt + (size_t)u0 * 128 + 8 * l4);
            float f0, f1;
            if (EDGE_NS) {
                unpack2(v0.x, f0, f1); a0[0] = fmaf(s0, f0, a0[0]); a0[1] = fmaf(s0, f1, a0[1]);
                unpack2(v0.y, f0, f1); a0[2] = fmaf(s0, f0, a0[2]); a0[3] = fmaf(s0, f1, a0[3]);
                unpack2(v0.z, f0, f1); a0[4] = fmaf(s0, f0, a0[4]); a0[5] = fmaf(s0, f1, a0[5]);
                unpack2(v0.w, f0, f1); a0[6] = fmaf(s0, f0, a0[6]); a0[7] = fmaf(s0, f1, a0[7]);
            } else {
                unpack2(v0.x, f0, f1); a0[0] += f0; a0[1] += f1;
                unpack2(v0.y, f0, f1); a0[2] += f0; a0[3] += f1;
                unpack2(v0.z, f0, f1); a0[4] += f0; a0[5] += f1;
                unpack2(v0.w, f0, f1); a0[6] += f0; a0[7] += f1;
            }
        }
        float nd = norm_dst[vi];
        float sc = ACT_NS ? norm_src[vi] : 1.f;
        const float* bp = bias + 8 * l4;
        unsigned p[4];
        #pragma unroll
        for (int q = 0; q < 4; ++q) {
            float lo = fmaxf(fmaf(nd, a0[2 * q]     + a1[2 * q],     bp[2 * q]),     0.f) * sc;
            float hi = fmaxf(fmaf(nd, a0[2 * q + 1] + a1[2 * q + 1], bp[2 * q + 1]), 0.f) * sc;
            p[q] = (unsigned)f2bf(lo) | ((unsigned)f2bf(hi) << 16);
        }
        *reinterpret_cast<uint4*>(&Xl[lrow][8 * l4]) = make_uint4(p[0], p[1], p[2], p[3]);
    } else {
        *reinterpret_cast<uint4*>(&Xl[lrow][8 * l4]) = make_uint4(0, 0, 0, 0);
    }
    __syncthreads();
    constexpr int FPW = NF_TOT / 4;
    const v8s* bp2 = reinterpret_cast<const v8s*>(Wf);
    int kgrp = lane >> 4;
    v4f acc[FPW];
    #pragma unroll
    for (int f = 0; f < FPW; ++f) acc[f] = (v4f){0.f, 0.f, 0.f, 0.f};
    #pragma unroll
    for (int ks = 0; ks < 4; ++ks) {
        v8s a = *reinterpret_cast<const v8s*>(&Xl[lane & 15][(ks * 4 + kgrp) * 8]);
        #pragma unroll
        for (int f = 0; f < FPW; ++f) {
            int F = wv * FPW + f;
            v8s b = bp2[(ks * NF_TOT + F) * 64 + lane];
            acc[f] = __builtin_amdgcn_mfma_f32_16x16x32_bf16(a, b, acc[f], 0, 0, 0);
        }
    }
    int rbase = row0 + (lane >> 4) * 4;
    int ccol = lane & 15;
    constexpr int OS = OUT40 ? 40 : NF_TOT * 16;
    #pragma unroll
    for (int r = 0; r < 4; ++r) {
        int gr = rbase + r;
        if (gr < n) {
            float s = MM_NS ? norm_src[gr] : 1.f;
            #pragma unroll
            for (int f = 0; f < FPW; ++f) {
                int colo = (wv * FPW + f) * 16 + ccol;
                if (!OUT40 || colo < 40)
                    out[(size_t)gr * OS + colo] = f2bf(s * acc[f][r]);
            }
        }
    }
}

// ---------------- D8: agg40, octant-per-node, packed 80-B rows ----------------
// Octant o of wave wv owns node blockIdx*32 + wv*8 + o; lanes l8<5 load
// 16B chunks (dims 8*l8..+7) of the 40-bf16 row; 2-deep unroll; 0 shuffles.
__global__ __launch_bounds__(256) void agg40_kernel(const ushort* __restrict__ yb,
        const int* __restrict__ row_ptr, const int* __restrict__ col,
        const float* __restrict__ norm_dst, const float* __restrict__ b3,
        float* __restrict__ out, int n) {
    int t = threadIdx.x;
    int wv = t >> 6, lane = t & 63;
    int oct = lane >> 3, l8 = lane & 7;
    int vi = (int)blockIdx.x * 32 + wv * 8 + oct;
    if (vi >= n) return;
    int start = row_ptr[vi], end = row_ptr[vi + 1];
    float a0[8], a1[8];
    #pragma unroll
    for (int i = 0; i < 8; ++i) { a0[i] = 0.f; a1[i] = 0.f; }
    if (l8 < 5) {
        int e = start;
        for (; e + 2 <= end; e += 2) {
            int u0 = col[e], u1 = col[e + 1];
            const uint4 v0 = *reinterpret_cast<const uint4*>(yb + (size_t)u0 * 40 + 8 * l8);
            const uint4 v1 = *reinterpret_cast<const uint4*>(yb + (size_t)u1 * 40 + 8 * l8);
            float f0, f1;
            unpack2(v0.x, f0, f1); a0[0] += f0; a0[1] += f1;
            unpack2(v0.y, f0, f1); a0[2] += f0; a0[3] += f1;
            unpack2(v0.z, f0, f1); a0[4] += f0; a0[5] += f1;
            unpack2(v0.w, f0, f1); a0[6] += f0; a0[7] += f1;
            unpack2(v1.x, f0, f1); a1[0] += f0; a1[1] += f1;
            unpack2(v1.y, f0, f1); a1[2] += f0; a1[3] += f1;
            unpack2(v1.z, f0, f1); a1[4] += f0; a1[5] += f1;
            unpack2(v1.w, f0, f1); a1[6] += f0; a1[7] += f1;
        }
        if (e < end) {
            int u0 = col[e];
            const uint4 v0 = *reinterpret_cast<const uint4*>(yb + (size_t)u0 * 40 + 8 * l8);
            float f0, f1;
            unpack2(v0.x, f0, f1); a0[0] += f0; a0[1] += f1;
            unpack2(v0.y, f0, f1); a0[2] += f0; a0[3] += f1;
            unpack2(v0.z, f0, f1); a0[4] += f0; a0[5] += f1;
            unpack2(v0.w, f0, f1); a0[6] += f0; a0[7] += f1;
        }
        float nd = norm_dst[vi];
        const float* bp = b3 + 8 * l8;
        float* op = out + (size_t)vi * 40 + 8 * l8;
        float4 o0, o1;
        o0.x = fmaf(nd, a0[0] + a1[0], bp[0]); o0.y = fmaf(nd, a0[1] + a1[1], bp[1]);
        o0.z = fmaf(nd, a0[2] + a1[2], bp[2]); o0.w = fmaf(nd, a0[3] + a1[3], bp[3]);
        o1.x = fmaf(nd, a0[4] + a1[4], bp[4]); o1.y = fmaf(nd, a0[5] + a1[5], bp[5]);
        o1.z = fmaf(nd, a0[6] + a1[6], bp[6]); o1.w = fmaf(nd, a0[7] + a1[7], bp[7]);
        *reinterpret_cast<float4*>(op)     = o0;
        *reinterpret_cast<float4*>(op + 4) = o1;
    }
}

extern "C" void kernel_launch(void* const* d_in, const int* in_sizes, int n_in,
                              void* d_out, int out_size, void* d_ws, size_t ws_size,
                              hipStream_t stream) {
    const float* features = (const float*)d_in[0];
    const int*   ei       = (const int*)d_in[1];
    const float* W1 = (const float*)d_in[2];
    const float* b1 = (const float*)d_in[3];
    const float* W2 = (const float*)d_in[4];
    const float* b2 = (const float*)d_in[5];
    const float* W3 = (const float*)d_in[6];
    const float* b3 = (const float*)d_in[7];

    const int n = in_sizes[0] / 128;
    const int E = in_sizes[1] / 2;

    const int nblk1 = (E + EPB - 1) / EPB;
    const int NB    = (n + 255) >> 8;
    const int L     = NB * nblk1;
    const int L2    = 2 * L;
    const int sb2   = (L2 + SCAN_CHUNK - 1) / SCAN_CHUNK;

    char* w = (char*)d_ws;
    auto alloc = [&](size_t bytes) {
        char* p = w;
        w += (bytes + 255) & ~(size_t)255;
        return p;
    };
    int*    hist_all = (int*)   alloc((size_t)L2 * 4);
    int*    partials = (int*)   alloc((size_t)256 * 4);
    float*  norm_src = (float*) alloc((size_t)n * 4);
    float*  norm_dst = (float*) alloc((size_t)n * 4);
    int*    row_ptr  = (int*)   alloc((size_t)(n + 1) * 4);
    int*    col      = (int*)   alloc((size_t)E * 4);
    ushort* xb1      = (ushort*)alloc((size_t)n * 128 * 2);
    ushort* xb2      = (ushort*)alloc((size_t)n * 128 * 2);
    char*   scratch  = (char*)  alloc((size_t)12 * E);       // CSR scratch; yb aliases after D5
    ushort* W1f      = (ushort*)alloc((size_t)16384 * 2);
    ushort* W2f      = (ushort*)alloc((size_t)16384 * 2);
    ushort* W3f      = (ushort*)alloc((size_t)8192 * 2);

    char* scr = scratch;
    ushort*        rankD = (ushort*)scr;                 scr += ((size_t)E * 2 + 255) & ~(size_t)255;
    ushort*        rankS = (ushort*)scr;                 scr += ((size_t)E * 2 + 255) & ~(size_t)255;
    unsigned*      packD = (unsigned*)scr;               scr += ((size_t)E * 4 + 255) & ~(size_t)255;
    unsigned char* srcb  = (unsigned char*)scr;
    ushort* yb = (ushort*)scratch;  // packed 80-B rows (n*40*2 = 4MB); reuses dead CSR scratch

    int mmb  = (n + 63) / 64;      // mm1 tiles (4 waves x 16 rows)
    int fb   = (n + 15) / 16;      // fused agg+mm blocks (16 nodes each)
    int ab40 = (n + 31) / 32;      // agg40 blocks (32 nodes each)

    front_kernel<<<nblk1 + 20, 256, 0, stream>>>(ei, E, nblk1, NB, hist_all,
                                                 rankD, rankS, W1, W2, W3, W1f, W2f, W3f);
    scanA_kernel<<<sb2, 256, 0, stream>>>(hist_all, L2, partials);
    scanC_kernel<<<sb2, 256, 0, stream>>>(hist_all, L2, partials);
    scatter_mm1_kernel<<<nblk1 + mmb, 256, 0, stream>>>(ei, E, nblk1, NB, hist_all,
                                                        rankD, rankS, packD, srcb,
                                                        features, W1f, xb1, n);
    bucket_kernel<<<2 * NB, 256, 0, stream>>>(packD, srcb, hist_all, nblk1, NB, n, E,
                                              row_ptr, col, norm_src, norm_dst);
    aggmm_kernel<1, 0, 8, 1, 0><<<fb, 256, 0, stream>>>(xb1, row_ptr, col, b1,
                                                        norm_dst, norm_src, W2f, xb2, n);
    aggmm_kernel<0, 1, 4, 0, 1><<<fb, 256, 0, stream>>>(xb2, row_ptr, col, b2,
                                                        norm_dst, norm_src, W3f, yb, n);
    agg40_kernel<<<ab40, 256, 0, stream>>>(yb, row_ptr, col, norm_dst, b3, (float*)d_out, n);
}